// Round 11
// baseline (193.224 us; speedup 1.0000x reference)
//
#include <hip/hip_runtime.h>
#include <math.h>

// B=4, C=64, OUT=64, H=256, W=256, M1=32, M2=32, HID=64, COORD=65

typedef __attribute__((ext_vector_type(8))) short bf16x8;
typedef __attribute__((ext_vector_type(4))) float f32x4;

// Fast exact-erf GELU: Abramowitz-Stegun 7.1.26, |eps_erf| <= 1.5e-7.
__device__ __forceinline__ float gelu_f(float v) {
    const float u = v * 0.70710678118654752440f;
    const float xa = fabsf(u);
    const float t = __builtin_amdgcn_rcpf(fmaf(0.3275911f, xa, 1.0f));
    float p = fmaf(1.061405429f, t, -1.453152027f);
    p = fmaf(p, t, 1.421413741f);
    p = fmaf(p, t, -0.284496736f);
    p = fmaf(p, t, 0.254829592f);
    p *= t;
    const float e = __expf(-xa * xa);
    float erfv = fmaf(-p, e, 1.0f);
    erfv = (u < 0.0f) ? -erfv : erfv;
    return 0.5f * v * (1.0f + erfv);
}

__device__ __forceinline__ unsigned short f2b(float f) {
    union { float f; unsigned int u; } v; v.f = f;
    unsigned int u = v.u + 0x7FFFu + ((v.u >> 16) & 1u);   // RNE
    return (unsigned short)(u >> 16);
}
__device__ __forceinline__ float b2f(unsigned short b) {
    union { unsigned int u; float f; } v; v.u = ((unsigned int)b) << 16;
    return v.f;
}

// ---------------------------------------------------------------------------
// 4x4 butterfly transpose within 4-lane clusters (lane^1, lane^2).
// ---------------------------------------------------------------------------
__device__ __forceinline__ ushort4 butterfly_xT(const float4 v, int q) {
    const float bx = __shfl_xor(v.x, 1);
    const float by = __shfl_xor(v.y, 1);
    const float bz = __shfl_xor(v.z, 1);
    const float bw = __shfl_xor(v.w, 1);
    float4 s1;
    s1.x = ((q & 1) == 0) ? v.x : by;
    s1.y = ((q & 1) == 0) ? bx  : v.y;
    s1.z = ((q & 1) == 0) ? v.z : bw;
    s1.w = ((q & 1) == 0) ? bz  : v.w;
    const float cx = __shfl_xor(s1.x, 2);
    const float cy = __shfl_xor(s1.y, 2);
    const float cz = __shfl_xor(s1.z, 2);
    const float cw = __shfl_xor(s1.w, 2);
    float4 s2;
    s2.x = ((q & 2) == 0) ? s1.x : cz;
    s2.y = ((q & 2) == 0) ? s1.y : cw;
    s2.z = ((q & 2) == 0) ? cx   : s1.z;
    s2.w = ((q & 2) == 0) ? cy   : s1.w;
    ushort4 u;
    u.x = f2b(s2.x); u.y = f2b(s2.y); u.z = f2b(s2.z); u.w = f2b(s2.w);
    return u;
}

// ---------------------------------------------------------------------------
// K_prep: transpose + bf16-convert MLP weights. wT[o][k] = W[k][o]. K0 pad->96.
// ---------------------------------------------------------------------------
__global__ void k_prep(const float* __restrict__ wW0, const float* __restrict__ wW1,
                       const float* __restrict__ wW2,
                       const float* __restrict__ hW0, const float* __restrict__ hW1,
                       const float* __restrict__ hW2,
                       unsigned short* __restrict__ wT0, unsigned short* __restrict__ wT1,
                       unsigned short* __restrict__ wT2,
                       unsigned short* __restrict__ hT0, unsigned short* __restrict__ hT1,
                       unsigned short* __restrict__ hT2)
{
    const int t = threadIdx.x;
    for (int idx = t; idx < 64 * 96; idx += 256) {
        const int o = idx / 96, k = idx % 96;
        wT0[idx] = (k < 65) ? f2b(wW0[k * 64 + o]) : (unsigned short)0;
        hT0[idx] = (k < 65) ? f2b(hW0[k * 64 + o]) : (unsigned short)0;
    }
    for (int idx = t; idx < 4096; idx += 256) {
        const int o = idx >> 6, k = idx & 63;
        wT1[idx] = f2b(wW1[k * 64 + o]);
        wT2[idx] = f2b(wW2[k * 64 + o]);
        hT1[idx] = f2b(hW1[k * 64 + o]);
        hT2[idx] = f2b(hW2[k * 64 + o]);
    }
}

// generic partial-sum
__global__ __launch_bounds__(256) void k_psum(const float* __restrict__ src,
                                              float* __restrict__ dst,
                                              int nparts, int part_stride)
{
    const int i = (blockIdx.x * 256 + threadIdx.x) * 4;
    float4 acc = *(const float4*)&src[i];
    for (int p = 1; p < nparts; ++p) {
        const float4 v = *(const float4*)&src[(size_t)p * part_stride + i];
        acc.x += v.x; acc.y += v.y; acc.z += v.z; acc.w += v.w;
    }
    *(float4*)&dst[i] = acc;
}

// psum for proc + repack to procT[((b*32+m)*32+k)*64+o] (re || im at +262144).
__global__ __launch_bounds__(256) void k_psum_procT(const float* __restrict__ src,
                                                    float* __restrict__ dst)
{
    const int idx = blockIdx.x * 256 + threadIdx.x;
    const int o = idx & 63, k = (idx >> 6) & 31, m = (idx >> 11) & 31, b = idx >> 16;
    const size_t in = (size_t)(b * 64 + o) * 1024 + k * 32 + m;
    const float re = src[in] + src[524288 + in];
    const float im = src[262144 + in] + src[524288 + 262144 + in];
    dst[idx] = re;
    dst[262144 + idx] = im;
}

// ---------------------------------------------------------------------------
// Reg-weight MFMA MLP layer, swizzled stride-96 act tiles.
// Swizzle (per row): 16B-chunk ch<8 -> ch^(row&7); ch>=8 -> 8+((ch-8)^(row&3)).
// Weight A-fragments live in registers (wf[kc]); bias in bv.
// ---------------------------------------------------------------------------
template<bool GELU, int NKC>
__device__ __forceinline__ void mfma_layer_r(
    const bf16x8* __restrict__ wf,
    const unsigned short* __restrict__ sAct,
    unsigned short* __restrict__ dst,
    const float4 bv, int arow, int g, int wv)
{
    const int crow = 16 * wv + g * 4;
    const int sx7 = arow & 7, sx3 = arow & 3;
    const f32x4 zero = {0.f, 0.f, 0.f, 0.f};
    f32x4 acc[4] = {zero, zero, zero, zero};
#pragma unroll
    for (int kc = 0; kc < NKC; ++kc) {
        const int chraw = kc * 4 + g;
        const int ch = (chraw < 8) ? (chraw ^ sx7) : (8 + ((chraw - 8) ^ sx3));
#pragma unroll
        for (int nt = 0; nt < 4; ++nt) {
            const bf16x8 b = *(const bf16x8*)&sAct[(nt * 16 + arow) * 96 + ch * 8];
            acc[nt] = __builtin_amdgcn_mfma_f32_16x16x32_bf16(wf[kc], b, acc[nt], 0, 0, 0);
        }
    }
    const int chw = (crow >> 3) ^ sx7;
#pragma unroll
    for (int nt = 0; nt < 4; ++nt) {
        const int px = nt * 16 + arow;
        float v0 = acc[nt][0] + bv.x;
        float v1 = acc[nt][1] + bv.y;
        float v2 = acc[nt][2] + bv.z;
        float v3 = acc[nt][3] + bv.w;
        if (GELU) { v0 = gelu_f(v0); v1 = gelu_f(v1); v2 = gelu_f(v2); v3 = gelu_f(v3); }
        ushort4 u;
        u.x = f2b(v0); u.y = f2b(v1); u.z = f2b(v2); u.w = f2b(v3);
        *(ushort4*)&dst[px * 96 + chw * 8 + (crow & 7)] = u;
    }
}

// ---------------------------------------------------------------------------
// K1+K2 fused: wb MLP + tfw. Reg-weights, 5 barriers/tile, LDS 40,960 B.
// grid = B*H (1024), 256 threads. Also emits xT_bf[b,h][w][c] (plain bf16).
// ---------------------------------------------------------------------------
__global__ __launch_bounds__(256) void k_wbtfw(
    const float* __restrict__ x,
    const unsigned short* __restrict__ wT0, const float* __restrict__ b0,
    const unsigned short* __restrict__ wT1, const float* __restrict__ b1,
    const unsigned short* __restrict__ wT2, const float* __restrict__ b2,
    unsigned short* __restrict__ wb_bf, unsigned short* __restrict__ xT_bf,
    float* __restrict__ tfwM)
{
    __shared__ __align__(16) unsigned short smem[20480];  // 40,960 B
    unsigned short* sA   = smem;              // [64][96] swizzled
    unsigned short* sB   = smem + 6144;       // [64][96] swizzled
    unsigned short* sXt  = smem + 12288;      // [64][64] swizzled x rows
    unsigned short* sWBt = smem + 16384;      // [64][64] swizzled wb^T rows

    const int bh = blockIdx.x;
    const int b = bh >> 8, h = bh & 255;
    const int t = threadIdx.x;
    const int lane = t & 63, wv = t >> 6;
    const int arow = lane & 15, g = lane >> 4;
    const int crow = 16 * wv + g * 4;
    const int sx7 = arow & 7;
    const f32x4 zero = {0.f, 0.f, 0.f, 0.f};

    // weights -> registers (once per block; wT* are L2-resident)
    const int wrow = 16 * wv + arow;
    bf16x8 w0f[3], w1f[2], w2f[2];
#pragma unroll
    for (int kc = 0; kc < 3; ++kc)
        w0f[kc] = *(const bf16x8*)&wT0[wrow * 96 + (kc * 4 + g) * 8];
#pragma unroll
    for (int kc = 0; kc < 2; ++kc) {
        w1f[kc] = *(const bf16x8*)&wT1[wrow * 64 + (kc * 4 + g) * 8];
        w2f[kc] = *(const bf16x8*)&wT2[wrow * 64 + (kc * 4 + g) * 8];
    }
    const float4 bv0 = *(const float4*)&b0[crow];
    const float4 bv1 = *(const float4*)&b1[crow];
    const float4 bv2 = *(const float4*)&b2[crow];

    f32x4 atf[4] = {zero, zero, zero, zero};   // tfw accumulator across tiles

    for (int wq = 0; wq < 4; ++wq) {
        const int w0 = wq * 64;
        __syncthreads();   // protect sA/sXt/sB/sWBt from prior tile's readers
        // dual-stage x: sXt[c][w] + sA[px][c] (butterfly), both swizzled
        {
            const int q = lane & 3, wg = lane >> 2;
#pragma unroll
            for (int r = 0; r < 4; ++r) {
                const int cb = 16 * r + 4 * wv;
                const int c = cb + q;
                const float4 v = *(const float4*)&x[((size_t)(b * 64 + c) * 256 + h) * 256 + w0 + wg * 4];
                ushort4 ux;
                ux.x = f2b(v.x); ux.y = f2b(v.y); ux.z = f2b(v.z); ux.w = f2b(v.w);
                const int chx = (wg >> 1) ^ (c & 7);
                *(ushort4*)&sXt[c * 64 + chx * 8 + 4 * (wg & 1)] = ux;
                const ushort4 u = butterfly_xT(v, q);
                const int row = wg * 4 + q;   // == lane
                const int cha = (cb >> 3) ^ (row & 7);
                *(ushort4*)&sA[row * 96 + cha * 8 + (cb & 7)] = u;
            }
        }
        if (t < 64) {
            const uint4 z = {0, 0, 0, 0};
#pragma unroll
            for (int j = 0; j < 4; ++j)
                *(uint4*)&sA[t * 96 + (8 + (j ^ (t & 3))) * 8] = z;
            sA[t * 96 + (8 + (t & 3)) * 8] = f2b((float)(w0 + t) * (2.0f / 255.0f) - 1.0f);
        }
        __syncthreads();
        // xT_bf write-out (plain layout) — overlaps with L0 phase
        const size_t pixbase = (size_t)(b * 256 + h) * 256 + w0;
#pragma unroll
        for (int r = 0; r < 2; ++r) {
            const int idx = r * 256 + t;
            const int px = idx >> 3, f = idx & 7;
            *(uint4*)&xT_bf[(pixbase + px) * 64 + f * 8] =
                *(const uint4*)&sA[px * 96 + ((f ^ (px & 7)) << 3)];
        }
        mfma_layer_r<true, 3>(w0f, sA, sB, bv0, arow, g, wv);
        __syncthreads();
        mfma_layer_r<true, 2>(w1f, sB, sA, bv1, arow, g, wv);
        __syncthreads();
        // layer 2 inline: regs -> sB [px][o] and sWBt [o][px], swizzled
        {
            f32x4 acc[4] = {zero, zero, zero, zero};
#pragma unroll
            for (int kc = 0; kc < 2; ++kc) {
                const int ch = (kc * 4 + g) ^ sx7;
#pragma unroll
                for (int nt = 0; nt < 4; ++nt) {
                    const bf16x8 bb = *(const bf16x8*)&sA[(nt * 16 + arow) * 96 + ch * 8];
                    acc[nt] = __builtin_amdgcn_mfma_f32_16x16x32_bf16(w2f[kc], bb, acc[nt], 0, 0, 0);
                }
            }
            const int chw = (crow >> 3) ^ sx7;
#pragma unroll
            for (int nt = 0; nt < 4; ++nt) {
                const int px = nt * 16 + arow;
                ushort4 u;
                u.x = f2b(acc[nt][0] + bv2.x);
                u.y = f2b(acc[nt][1] + bv2.y);
                u.z = f2b(acc[nt][2] + bv2.z);
                u.w = f2b(acc[nt][3] + bv2.w);
                *(ushort4*)&sB[px * 96 + chw * 8 + (crow & 7)] = u;
                const int ph = px >> 3, pl = px & 7;
                sWBt[(crow + 0) * 64 + ((ph ^ ((crow + 0) & 7)) << 3) + pl] = u.x;
                sWBt[(crow + 1) * 64 + ((ph ^ ((crow + 1) & 7)) << 3) + pl] = u.y;
                sWBt[(crow + 2) * 64 + ((ph ^ ((crow + 2) & 7)) << 3) + pl] = u.z;
                sWBt[(crow + 3) * 64 + ((ph ^ ((crow + 3) & 7)) << 3) + pl] = u.w;
            }
        }
        __syncthreads();
        // wb_bf coalesced write (swizzled read) + tfw partial MFMA
#pragma unroll
        for (int r = 0; r < 2; ++r) {
            const int idx = r * 256 + t;
            const int px = idx >> 3, f = idx & 7;
            *(uint4*)&wb_bf[(pixbase + px) * 64 + f * 8] =
                *(const uint4*)&sB[px * 96 + ((f ^ (px & 7)) << 3)];
        }
#pragma unroll
        for (int kc = 0; kc < 2; ++kc) {
            const int ch = (kc * 4 + g) ^ sx7;
            const bf16x8 a = *(const bf16x8*)&sWBt[(16 * wv + arow) * 64 + ch * 8];
#pragma unroll
            for (int nt = 0; nt < 4; ++nt) {
                const bf16x8 bb = *(const bf16x8*)&sXt[(nt * 16 + arow) * 64 + ch * 8];
                atf[nt] = __builtin_amdgcn_mfma_f32_16x16x32_bf16(a, bb, atf[nt], 0, 0, 0);
            }
        }
    }

    // epilogue: scatter D[mo][c] -> f32 LDS [mo][68], coalesced tfwM write
    __syncthreads();
    float* sF = (float*)smem;   // 17,408 B fits in sA+sB region (24,576 B)
#pragma unroll
    for (int nt = 0; nt < 4; ++nt) {
        const int c = nt * 16 + arow;
#pragma unroll
        for (int j = 0; j < 4; ++j)
            sF[(crow + j) * 68 + c] = atf[nt][j];
    }
    __syncthreads();
#pragma unroll
    for (int r = 0; r < 4; ++r) {
        const int idx = r * 256 + t;
        const int m = idx >> 5, gg = idx & 31;
        float4 v;
        v.x = sF[m * 68 + gg * 2];
        v.y = sF[(m + 32) * 68 + gg * 2];
        v.z = sF[m * 68 + gg * 2 + 1];
        v.w = sF[(m + 32) * 68 + gg * 2 + 1];
        *(float4*)&tfwM[((size_t)(b * 32 + m) * 256 + h) * 128 + gg * 4] = v;
    }
}

// K3: hb basis, reg-weights + swizzled stride-96 tiles. grid = B*M2*4.
__global__ __launch_bounds__(256) void k_hb_mlp3(
    const float* __restrict__ tfwM,
    const unsigned short* __restrict__ hT0, const float* __restrict__ b0,
    const unsigned short* __restrict__ hT1, const float* __restrict__ b1,
    const unsigned short* __restrict__ hT2, const float* __restrict__ b2,
    unsigned short* __restrict__ hb_bf)
{
    __shared__ __align__(16) unsigned short sA[64 * 96];
    __shared__ __align__(16) unsigned short sB[64 * 96];
    const int blk = blockIdx.x;
    const int bm = blk >> 2, hq = blk & 3;
    const int h0 = hq * 64;
    const int t = threadIdx.x;
    const int lane = t & 63, wv = t >> 6;
    const int arow = lane & 15, g = lane >> 4;
    const int crow = 16 * wv + g * 4;

    const int wrow = 16 * wv + arow;
    bf16x8 h0f[3], h1f[2], h2f[2];
#pragma unroll
    for (int kc = 0; kc < 3; ++kc)
        h0f[kc] = *(const bf16x8*)&hT0[wrow * 96 + (kc * 4 + g) * 8];
#pragma unroll
    for (int kc = 0; kc < 2; ++kc) {
        h1f[kc] = *(const bf16x8*)&hT1[wrow * 64 + (kc * 4 + g) * 8];
        h2f[kc] = *(const bf16x8*)&hT2[wrow * 64 + (kc * 4 + g) * 8];
    }
    const float4 bv0 = *(const float4*)&b0[crow];
    const float4 bv1 = *(const float4*)&b1[crow];
    const float4 bv2 = *(const float4*)&b2[crow];

    // stage tfw real parts -> sA[p][c] swizzled
#pragma unroll
    for (int r = 0; r < 4; ++r) {
        const int idx = r * 256 + t;
        const int p = idx >> 4, f = idx & 15;
        const float* src = &tfwM[(size_t)(bm * 256 + h0 + p) * 128 + f * 8];
        const float4 u0 = *(const float4*)&src[0];
        const float4 u1 = *(const float4*)&src[4];
        ushort4 u;
        u.x = f2b(u0.x); u.y = f2b(u0.z); u.z = f2b(u1.x); u.w = f2b(u1.z);
        const int ch = (f >> 1) ^ (p & 7);
        *(ushort4*)&sA[p * 96 + ch * 8 + 4 * (f & 1)] = u;
    }
    if (t < 64) {
        const uint4 z = {0, 0, 0, 0};
#pragma unroll
        for (int j = 0; j < 4; ++j)
            *(uint4*)&sA[t * 96 + (8 + (j ^ (t & 3))) * 8] = z;
        sA[t * 96 + (8 + (t & 3)) * 8] = f2b((float)(h0 + t) * (2.0f / 255.0f) - 1.0f);
    }
    __syncthreads();
    mfma_layer_r<true, 3>(h0f, sA, sB, bv0, arow, g, wv);
    __syncthreads();
    mfma_layer_r<true, 2>(h1f, sB, sA, bv1, arow, g, wv);
    __syncthreads();
    mfma_layer_r<false, 2>(h2f, sA, sB, bv2, arow, g, wv);
    __syncthreads();

    const size_t pixbase = (size_t)bm * 256 + h0;
#pragma unroll
    for (int r = 0; r < 2; ++r) {
        const int idx = r * 256 + t;
        const int px = idx >> 3, f = idx & 7;
        *(uint4*)&hb_bf[(pixbase + px) * 64 + f * 8] =
            *(const uint4*)&sB[px * 96 + ((f ^ (px & 7)) << 3)];
    }
}

// K4: tfhw partials. grid = 1024: (bm, chalf, hq).
__global__ __launch_bounds__(256) void k_tfhw3(
    const float* __restrict__ tfwM,
    const unsigned short* __restrict__ hb_bf,
    float* __restrict__ tfhw_p)
{
    __shared__ float hr[64 * 32];
    __shared__ float hi2[64 * 32];
    __shared__ float slab[32 * 64];
    const int blk = blockIdx.x;
    const int bm = blk >> 3, chalf = (blk >> 2) & 1, hq = blk & 3;
    const int b = bm >> 5, m = bm & 31;
    const int t = threadIdx.x;
#pragma unroll
    for (int r = 0; r < 2; ++r) {
        const int q = r * 256 + t;
        const int hl = q >> 3, f = q & 7;
        const uint4 raw = *(const uint4*)&hb_bf[((size_t)bm * 256 + hq * 64 + hl) * 64 + f * 8];
        const unsigned short* us = (const unsigned short*)&raw;
        float v[8];
#pragma unroll
        for (int j = 0; j < 8; ++j) v[j] = b2f(us[j]);
        float* dst = (f < 4) ? &hr[hl * 32 + f * 8] : &hi2[hl * 32 + (f - 4) * 8];
        float4 lo; lo.x = v[0]; lo.y = v[1]; lo.z = v[2]; lo.w = v[3];
        float4 hi; hi.x = v[4]; hi.y = v[5]; hi.z = v[6]; hi.w = v[7];
        *(float4*)&dst[0] = lo;
        *(float4*)&dst[4] = hi;
    }
    const int k = t & 31, cq = t >> 5;
    float accr[4] = {0.f, 0.f, 0.f, 0.f}, acci[4] = {0.f, 0.f, 0.f, 0.f};
    const size_t tbase = (size_t)bm * 32768;
    for (int ht = 0; ht < 2; ++ht) {
        __syncthreads();
#pragma unroll
        for (int r = 0; r < 2; ++r) {
            const int q = r * 256 + t;
            const int hl = q >> 3, f = q & 7;
            *(float4*)&slab[hl * 64 + f * 4] =
                *(const float4*)&tfwM[tbase + (size_t)(hq * 64 + ht * 32 + hl) * 128 + chalf * 64 + f * 4];
        }
        __syncthreads();
#pragma unroll 8
        for (int hl = 0; hl < 32; ++hl) {
            const float hrv = hr[(ht * 32 + hl) * 32 + k];
            const float hiv = hi2[(ht * 32 + hl) * 32 + k];
            const float4 u0 = *(const float4*)&slab[hl * 64 + cq * 8];
            const float4 u1 = *(const float4*)&slab[hl * 64 + cq * 8 + 4];
            accr[0] = fmaf(u0.x, hrv, fmaf(-u0.y, hiv, accr[0]));
            acci[0] = fmaf(u0.x, hiv, fmaf( u0.y, hrv, acci[0]));
            accr[1] = fmaf(u0.z, hrv, fmaf(-u0.w, hiv, accr[1]));
            acci[1] = fmaf(u0.z, hiv, fmaf( u0.w, hrv, acci[1]));
            accr[2] = fmaf(u1.x, hrv, fmaf(-u1.y, hiv, accr[2]));
            acci[2] = fmaf(u1.x, hiv, fmaf( u1.y, hrv, acci[2]));
            accr[3] = fmaf(u1.z, hrv, fmaf(-u1.w, hiv, accr[3]));
            acci[3] = fmaf(u1.z, hiv, fmaf( u1.w, hrv, acci[3]));
        }
    }
    float* tp = tfhw_p + (size_t)hq * 524288;
#pragma unroll
    for (int i = 0; i < 4; ++i) {
        const int c = chalf * 32 + cq * 4 + i;
        const size_t po = ((size_t)(b * 64 + c) * 32 + k) * 32 + m;
        tp[po] = accr[i];
        tp[262144 + po] = acci[i];
    }
}

// K5: proc partials. grid = 512: (o, kq, chalf).
__global__ __launch_bounds__(256) void k_proc2(
    const float* __restrict__ tfhw,
    const float* __restrict__ Wf_re, const float* __restrict__ Wf_im,
    float* __restrict__ proc_p)
{
    const int blk = blockIdx.x;
    const int o = blk >> 3, kq = (blk >> 1) & 3, chalf = blk & 1;
    const int t = threadIdx.x;
    const int mo = kq * 256 + t;
    const float* tre = tfhw;
    const float* tim = tfhw + 262144;
    float accr[4] = {0.f, 0.f, 0.f, 0.f}, acci[4] = {0.f, 0.f, 0.f, 0.f};
    for (int cc = 0; cc < 32; ++cc) {
        const int c = chalf * 32 + cc;
        const float wfr = Wf_re[(size_t)(c * 64 + o) * 1024 + mo];
        const float wfi = Wf_im[(size_t)(c * 64 + o) * 1024 + mo];
#pragma unroll
        for (int bb = 0; bb < 4; ++bb) {
            const float tr = tre[(size_t)(bb * 64 + c) * 1024 + mo];
            const float ti = tim[(size_t)(bb * 64 + c) * 1024 + mo];
            accr[bb] = fmaf(tr, wfr, fmaf(-ti, wfi, accr[bb]));
            acci[bb] = fmaf(tr, wfi, fmaf(ti, wfr, acci[bb]));
        }
    }
    float* pp = proc_p + (size_t)chalf * 524288;
#pragma unroll
    for (int bb = 0; bb < 4; ++bb) {
        pp[(size_t)(bb * 64 + o) * 1024 + mo] = accr[bb];
        pp[262144 + (size_t)(bb * 64 + o) * 1024 + mo] = acci[bb];
    }
}

// K6: recO bf16. grid = 1024: (bm, hq8). Coalesced procT reads.
__global__ __launch_bounds__(256) void k_rec4(
    const float* __restrict__ procT,
    const unsigned short* __restrict__ hb_bf,
    unsigned short* __restrict__ recO)
{
    __shared__ float lhr[32 * 32];
    __shared__ float lhi[32 * 32];
    const int blk = blockIdx.x;
    const int bm = blk >> 3, hq = blk & 7;
    const int b = bm >> 5, m = bm & 31;
    const int t = threadIdx.x;
    {
        const int hl = t >> 3, f = t & 7;
        const uint4 raw = *(const uint4*)&hb_bf[((size_t)bm * 256 + hq * 32 + hl) * 64 + f * 8];
        const unsigned short* us = (const unsigned short*)&raw;
        float v[8];
#pragma unroll
        for (int j = 0; j < 8; ++j) v[j] = b2f(us[j]);
        float* dst = (f < 4) ? &lhr[hl * 32 + f * 8] : &lhi[hl * 32 + (f - 4) * 8];
        float4 lo; lo.x = v[0]; lo.y = v[1]; lo.z = v[2]; lo.w = v[3];
        float4 hi; hi.x = v[4]; hi.y = v[5]; hi.z = v[6]; hi.w = v[7];
        *(float4*)&dst[0] = lo;
        *(float4*)&dst[4] = hi;
    }
    const int o = t & 63, hg = t >> 6;
    const float* pr = procT + (size_t)(b * 32 + m) * 2048 + o;
    const float* pi = pr + 262144;
    float Pr[32], Pi[32];
#pragma unroll
    for (int k = 0; k < 32; ++k) {
        Pr[k] = pr[k * 64];
        Pi[k] = pi[k * 64];
    }
    __syncthreads();
    for (int hh = 0; hh < 8; ++hh) {
        const int hl = hg * 8 + hh;
        float ar = 0.f, ai = 0.f;
#pragma unroll
        for (int k4 = 0; k4 < 8; ++k4) {
            const float4 hr4 = *(const float4*)&lhr[hl * 32 + k4 * 4];
            const float4 hi4 = *(const float4*)&lhi[hl * 32 + k4 * 4];
            ar = fmaf(Pr[k4*4+0], hr4.x, fmaf(Pi[k4*4+0], hi4.x, ar));
            ai = fmaf(Pi[k4*4+0], hr4.x, fmaf(-Pr[k4*4+0], hi4.x, ai));
            ar = fmaf(Pr[k4*4+1], hr4.y, fmaf(Pi[k4*4+1], hi4.y, ar));
            ai = fmaf(Pi[k4*4+1], hr4.y, fmaf(-Pr[k4*4+1], hi4.y, ai));
            ar = fmaf(Pr[k4*4+2], hr4.z, fmaf(Pi[k4*4+2], hi4.z, ar));
            ai = fmaf(Pi[k4*4+2], hr4.z, fmaf(-Pr[k4*4+2], hi4.z, ai));
            ar = fmaf(Pr[k4*4+3], hr4.w, fmaf(Pi[k4*4+3], hi4.w, ar));
            ai = fmaf(Pi[k4*4+3], hr4.w, fmaf(-Pr[k4*4+3], hi4.w, ai));
        }
        const int h = hq * 32 + hl;
        const size_t rb = ((size_t)(b * 256 + h) * 64 + o) * 64;
        recO[rb + m]      = f2b(ar);
        recO[rb + 32 + m] = f2b(ai);
    }
}

// K7: MFMA fused final. grid = B*H*4. x staged from xT_bf (plain bf16 copies).
__global__ __launch_bounds__(256) void k_final4(
    const unsigned short* __restrict__ xT_bf,
    const unsigned short* __restrict__ wb_bf,
    const unsigned short* __restrict__ recO,
    const float* __restrict__ mw, const float* __restrict__ mb,
    const float* __restrict__ scw, const float* __restrict__ scb,
    float* __restrict__ out)
{
    constexpr int LD = 72;
    __shared__ __align__(16) unsigned short sWb[64 * LD];
    __shared__ __align__(16) unsigned short sR [64 * LD];
    __shared__ __align__(16) unsigned short sX [64 * LD];
    __shared__ __align__(16) unsigned short sS [64 * LD];
    const int blk = blockIdx.x;
    const int b = blk >> 10, h = (blk >> 2) & 255, wq = blk & 3;
    const int w0 = wq * 64;
    const int t = threadIdx.x;
    const int lane = t & 63, wv = t >> 6;
    const size_t pixbase = (size_t)(b * 256 + h) * 256 + w0;

#pragma unroll
    for (int r = 0; r < 2; ++r) {
        const int idx = r * 256 + t;
        const int px = idx >> 3, f = idx & 7;
        *(uint4*)&sWb[px * LD + f * 8] = *(const uint4*)&wb_bf[(pixbase + px) * 64 + f * 8];
    }
    const size_t recbase = (size_t)(b * 256 + h) * 4096;
#pragma unroll
    for (int r = 0; r < 2; ++r) {
        const int idx = r * 256 + t;
        const int o = idx >> 3, f = idx & 7;
        *(uint4*)&sR[o * LD + f * 8] = *(const uint4*)&recO[recbase + (size_t)o * 64 + f * 8];
    }
#pragma unroll
    for (int r = 0; r < 2; ++r) {
        const int idx = r * 256 + t;
        const int px = idx >> 3, f = idx & 7;
        *(uint4*)&sX[px * LD + f * 8] = *(const uint4*)&xT_bf[(pixbase + px) * 64 + f * 8];
    }
    __syncthreads();

    const int arow = lane & 15;
    const int koff = (lane >> 4) * 8;
    const f32x4 zero = {0.f, 0.f, 0.f, 0.f};

    f32x4 accA[4] = {zero, zero, zero, zero};
#pragma unroll
    for (int kc = 0; kc < 2; ++kc) {
        const bf16x8 a = *(const bf16x8*)&sR[(16 * wv + arow) * LD + kc * 32 + koff];
#pragma unroll
        for (int nt = 0; nt < 4; ++nt) {
            const bf16x8 bb = *(const bf16x8*)&sWb[(nt * 16 + arow) * LD + kc * 32 + koff];
            accA[nt] = __builtin_amdgcn_mfma_f32_16x16x32_bf16(a, bb, accA[nt], 0, 0, 0);
        }
    }
    __syncthreads();

    const int crow = 16 * wv + (lane >> 4) * 4;
#pragma unroll
    for (int nt = 0; nt < 4; ++nt) {
        const int px = nt * 16 + arow;
#pragma unroll
        for (int j = 0; j < 4; ++j)
            sS[px * LD + crow + j] = f2b(accA[nt][j] * (1.0f / 65536.0f));
    }
#pragma unroll
    for (int r = 0; r < 4; ++r) {
        const int idx = r * 256 + t;
        const int o = idx >> 4, cq = idx & 15;
        const float4 v1 = *(const float4*)&mw[o * 64 + cq * 4];
        ushort4 u1;
        u1.x = f2b(v1.x); u1.y = f2b(v1.y); u1.z = f2b(v1.z); u1.w = f2b(v1.w);
        *(ushort4*)&sWb[o * LD + cq * 4] = u1;
        const float4 v2 = *(const float4*)&scw[o * 64 + cq * 4];
        ushort4 u2;
        u2.x = f2b(v2.x); u2.y = f2b(v2.y); u2.z = f2b(v2.z); u2.w = f2b(v2.w);
        *(ushort4*)&sR[o * LD + cq * 4] = u2;
    }
    __syncthreads();

    f32x4 accB[4] = {zero, zero, zero, zero};
    f32x4 accC[4] = {zero, zero, zero, zero};
#pragma unroll
    for (int kc = 0; kc < 2; ++kc) {
        const bf16x8 am = *(const bf16x8*)&sWb[(16 * wv + arow) * LD + kc * 32 + koff];
        const bf16x8 as = *(const bf16x8*)&sR [(16 * wv + arow) * LD + kc * 32 + koff];
#pragma unroll
        for (int nt = 0; nt < 4; ++nt) {
            const bf16x8 bs = *(const bf16x8*)&sS[(nt * 16 + arow) * LD + kc * 32 + koff];
            const bf16x8 bx = *(const bf16x8*)&sX[(nt * 16 + arow) * LD + kc * 32 + koff];
            accB[nt] = __builtin_amdgcn_mfma_f32_16x16x32_bf16(am, bs, accB[nt], 0, 0, 0);
            accC[nt] = __builtin_amdgcn_mfma_f32_16x16x32_bf16(as, bx, accC[nt], 0, 0, 0);
        }
    }

#pragma unroll
    for (int nt = 0; nt < 4; ++nt) {
        const int px = nt * 16 + arow;
#pragma unroll
        for (int j = 0; j < 4; ++j) {
            const int o = crow + j;
            const float y = gelu_f(accB[nt][j] + mb[o]);
            const float z = y + accC[nt][j] + scb[o];
            out[((size_t)(b * 64 + o) * 256 + h) * 256 + w0 + px] = gelu_f(z);
        }
    }
}

extern "C" void kernel_launch(void* const* d_in, const int* in_sizes, int n_in,
                              void* d_out, int out_size, void* d_ws, size_t ws_size,
                              hipStream_t stream) {
    const float* x    = (const float*)d_in[0];
    const float* wW0  = (const float*)d_in[1];
    const float* wb0  = (const float*)d_in[2];
    const float* wW1  = (const float*)d_in[3];
    const float* wb1  = (const float*)d_in[4];
    const float* wW2  = (const float*)d_in[5];
    const float* wb2  = (const float*)d_in[6];
    const float* hW0  = (const float*)d_in[7];
    const float* hb0  = (const float*)d_in[8];
    const float* hW1  = (const float*)d_in[9];
    const float* hb1  = (const float*)d_in[10];
    const float* hW2  = (const float*)d_in[11];
    const float* hb2  = (const float*)d_in[12];
    const float* Wf_re = (const float*)d_in[13];
    const float* Wf_im = (const float*)d_in[14];
    const float* mw   = (const float*)d_in[15];
    const float* mbv  = (const float*)d_in[16];
    const float* scw  = (const float*)d_in[17];
    const float* scb  = (const float*)d_in[18];

    char* base = (char*)d_ws;
    unsigned short* wb_bf = (unsigned short*)(base + 0);            // 33,554,432
    unsigned short* xT_bf = (unsigned short*)(base + 33554432);     // 33,554,432
    float* tfwM   = (float*)(base + 67108864);                      // 16,777,216
    unsigned short* hb_bf = (unsigned short*)(base + 83886080);     //  4,194,304
    float* tfhw_p = (float*)(base + 88080384);                      //  8,388,608 (4 parts)
    float* tfhw   = (float*)(base + 96468992);                      //  2,097,152 (re||im)
    float* proc_p = (float*)(base + 98566144);                      //  4,194,304 (2 parts)
    float* procT  = (float*)(base + 102760448);                     //  2,097,152 (re||im)
    unsigned short* recO = (unsigned short*)(base + 104857600);     //  8,388,608
    unsigned short* wT0 = (unsigned short*)(base + 113246208);      //     12,288
    unsigned short* wT1 = (unsigned short*)(base + 113258496);      //      8,192
    unsigned short* wT2 = (unsigned short*)(base + 113266688);
    unsigned short* hT0 = (unsigned short*)(base + 113274880);
    unsigned short* hT1 = (unsigned short*)(base + 113287168);
    unsigned short* hT2 = (unsigned short*)(base + 113295360);
    // total ~113.3 MB

    k_prep<<<1, 256, 0, stream>>>(wW0, wW1, wW2, hW0, hW1, hW2,
                                  wT0, wT1, wT2, hT0, hT1, hT2);
    k_wbtfw<<<1024, 256, 0, stream>>>(x, wT0, wb0, wT1, wb1, wT2, wb2,
                                      wb_bf, xT_bf, tfwM);
    k_hb_mlp3<<<512, 256, 0, stream>>>(tfwM, hT0, hb0, hT1, hb1, hT2, hb2, hb_bf);
    k_tfhw3<<<1024, 256, 0, stream>>>(tfwM, hb_bf, tfhw_p);
    k_psum<<<1024, 256, 0, stream>>>(tfhw_p, tfhw, 4, 524288);
    k_proc2<<<512, 256, 0, stream>>>(tfhw, Wf_re, Wf_im, proc_p);
    k_psum_procT<<<1024, 256, 0, stream>>>(proc_p, procT);
    k_rec4<<<1024, 256, 0, stream>>>(procT, hb_bf, recO);
    k_final4<<<4096, 256, 0, stream>>>(xT_bf, wb_bf, recO, mw, mbv, scw, scb,
                                       (float*)d_out);
}

// Round 12
// 180.148 us; speedup vs baseline: 1.0726x; 1.0726x over previous
//
#include <hip/hip_runtime.h>
#include <math.h>

// B=4, C=64, OUT=64, H=256, W=256, M1=32, M2=32, HID=64, COORD=65

typedef __attribute__((ext_vector_type(8))) short bf16x8;
typedef __attribute__((ext_vector_type(4))) float f32x4;

// Fast exact-erf GELU: Abramowitz-Stegun 7.1.26, |eps_erf| <= 1.5e-7.
__device__ __forceinline__ float gelu_f(float v) {
    const float u = v * 0.70710678118654752440f;
    const float xa = fabsf(u);
    const float t = __builtin_amdgcn_rcpf(fmaf(0.3275911f, xa, 1.0f));
    float p = fmaf(1.061405429f, t, -1.453152027f);
    p = fmaf(p, t, 1.421413741f);
    p = fmaf(p, t, -0.284496736f);
    p = fmaf(p, t, 0.254829592f);
    p *= t;
    const float e = __expf(-xa * xa);
    float erfv = fmaf(-p, e, 1.0f);
    erfv = (u < 0.0f) ? -erfv : erfv;
    return 0.5f * v * (1.0f + erfv);
}

__device__ __forceinline__ unsigned short f2b(float f) {
    union { float f; unsigned int u; } v; v.f = f;
    unsigned int u = v.u + 0x7FFFu + ((v.u >> 16) & 1u);   // RNE
    return (unsigned short)(u >> 16);
}
__device__ __forceinline__ float b2f(unsigned short b) {
    union { unsigned int u; float f; } v; v.u = ((unsigned int)b) << 16;
    return v.f;
}

// ---------------------------------------------------------------------------
// 4x4 butterfly transpose within 4-lane clusters (lane^1, lane^2).
// ---------------------------------------------------------------------------
__device__ __forceinline__ ushort4 butterfly_xT(const float4 v, int q) {
    const float bx = __shfl_xor(v.x, 1);
    const float by = __shfl_xor(v.y, 1);
    const float bz = __shfl_xor(v.z, 1);
    const float bw = __shfl_xor(v.w, 1);
    float4 s1;
    s1.x = ((q & 1) == 0) ? v.x : by;
    s1.y = ((q & 1) == 0) ? bx  : v.y;
    s1.z = ((q & 1) == 0) ? v.z : bw;
    s1.w = ((q & 1) == 0) ? bz  : v.w;
    const float cx = __shfl_xor(s1.x, 2);
    const float cy = __shfl_xor(s1.y, 2);
    const float cz = __shfl_xor(s1.z, 2);
    const float cw = __shfl_xor(s1.w, 2);
    float4 s2;
    s2.x = ((q & 2) == 0) ? s1.x : cz;
    s2.y = ((q & 2) == 0) ? s1.y : cw;
    s2.z = ((q & 2) == 0) ? cx   : s1.z;
    s2.w = ((q & 2) == 0) ? cy   : s1.w;
    ushort4 u;
    u.x = f2b(s2.x); u.y = f2b(s2.y); u.z = f2b(s2.z); u.w = f2b(s2.w);
    return u;
}

// Stage x^T into LDS [w_local][c] bf16 (stride LD, plain layout) for k_final4.
__device__ __forceinline__ void stage_xT(const float* __restrict__ x,
    unsigned short* __restrict__ sA, int b, int h, int w0, int t, int LD)
{
    const int lane = t & 63, wv = t >> 6;
    const int q = lane & 3, wg = lane >> 2;
#pragma unroll
    for (int r = 0; r < 4; ++r) {
        const int cb = (r * 4 + wv) * 4;
        const float4 v = *(const float4*)&x[((size_t)(b * 64 + cb + q) * 256 + h) * 256 + w0 + wg * 4];
        const ushort4 u = butterfly_xT(v, q);
        *(ushort4*)&sA[(wg * 4 + q) * LD + cb] = u;
    }
}

// ---------------------------------------------------------------------------
// K_prep: transpose + bf16-convert MLP weights. wT[o][k] = W[k][o]. K0 pad->96.
// ---------------------------------------------------------------------------
__global__ void k_prep(const float* __restrict__ wW0, const float* __restrict__ wW1,
                       const float* __restrict__ wW2,
                       const float* __restrict__ hW0, const float* __restrict__ hW1,
                       const float* __restrict__ hW2,
                       unsigned short* __restrict__ wT0, unsigned short* __restrict__ wT1,
                       unsigned short* __restrict__ wT2,
                       unsigned short* __restrict__ hT0, unsigned short* __restrict__ hT1,
                       unsigned short* __restrict__ hT2)
{
    const int t = threadIdx.x;
    for (int idx = t; idx < 64 * 96; idx += 256) {
        const int o = idx / 96, k = idx % 96;
        wT0[idx] = (k < 65) ? f2b(wW0[k * 64 + o]) : (unsigned short)0;
        hT0[idx] = (k < 65) ? f2b(hW0[k * 64 + o]) : (unsigned short)0;
    }
    for (int idx = t; idx < 4096; idx += 256) {
        const int o = idx >> 6, k = idx & 63;
        wT1[idx] = f2b(wW1[k * 64 + o]);
        wT2[idx] = f2b(wW2[k * 64 + o]);
        hT1[idx] = f2b(hW1[k * 64 + o]);
        hT2[idx] = f2b(hW2[k * 64 + o]);
    }
}

// generic partial-sum
__global__ __launch_bounds__(256) void k_psum(const float* __restrict__ src,
                                              float* __restrict__ dst,
                                              int nparts, int part_stride)
{
    const int i = (blockIdx.x * 256 + threadIdx.x) * 4;
    float4 acc = *(const float4*)&src[i];
    for (int p = 1; p < nparts; ++p) {
        const float4 v = *(const float4*)&src[(size_t)p * part_stride + i];
        acc.x += v.x; acc.y += v.y; acc.z += v.z; acc.w += v.w;
    }
    *(float4*)&dst[i] = acc;
}

// psum for proc + repack to procT[((b*32+m)*32+k)*64+o] (re || im at +262144).
__global__ __launch_bounds__(256) void k_psum_procT(const float* __restrict__ src,
                                                    float* __restrict__ dst)
{
    const int idx = blockIdx.x * 256 + threadIdx.x;
    const int o = idx & 63, k = (idx >> 6) & 31, m = (idx >> 11) & 31, b = idx >> 16;
    const size_t in = (size_t)(b * 64 + o) * 1024 + k * 32 + m;
    const float re = src[in] + src[524288 + in];
    const float im = src[262144 + in] + src[524288 + 262144 + in];
    dst[idx] = re;
    dst[262144 + idx] = im;
}

// ---------------------------------------------------------------------------
// Reg-weight MFMA MLP layer, swizzled stride-96 act tiles.
// Swizzle (per row): 16B-chunk ch<8 -> ch^(row&7); ch>=8 -> 8+((ch-8)^(row&3)).
// ---------------------------------------------------------------------------
template<bool GELU, int NKC>
__device__ __forceinline__ void mfma_layer_r(
    const bf16x8* __restrict__ wf,
    const unsigned short* __restrict__ sAct,
    unsigned short* __restrict__ dst,
    const float4 bv, int arow, int g, int wv)
{
    const int crow = 16 * wv + g * 4;
    const int sx7 = arow & 7, sx3 = arow & 3;
    const f32x4 zero = {0.f, 0.f, 0.f, 0.f};
    f32x4 acc[4] = {zero, zero, zero, zero};
#pragma unroll
    for (int kc = 0; kc < NKC; ++kc) {
        const int chraw = kc * 4 + g;
        const int ch = (chraw < 8) ? (chraw ^ sx7) : (8 + ((chraw - 8) ^ sx3));
#pragma unroll
        for (int nt = 0; nt < 4; ++nt) {
            const bf16x8 b = *(const bf16x8*)&sAct[(nt * 16 + arow) * 96 + ch * 8];
            acc[nt] = __builtin_amdgcn_mfma_f32_16x16x32_bf16(wf[kc], b, acc[nt], 0, 0, 0);
        }
    }
    const int chw = (crow >> 3) ^ sx7;
#pragma unroll
    for (int nt = 0; nt < 4; ++nt) {
        const int px = nt * 16 + arow;
        float v0 = acc[nt][0] + bv.x;
        float v1 = acc[nt][1] + bv.y;
        float v2 = acc[nt][2] + bv.z;
        float v3 = acc[nt][3] + bv.w;
        if (GELU) { v0 = gelu_f(v0); v1 = gelu_f(v1); v2 = gelu_f(v2); v3 = gelu_f(v3); }
        ushort4 u;
        u.x = f2b(v0); u.y = f2b(v1); u.z = f2b(v2); u.w = f2b(v3);
        *(ushort4*)&dst[px * 96 + chw * 8 + (crow & 7)] = u;
    }
}

// ---------------------------------------------------------------------------
// K1+K2 fused: wb MLP + tfw. Reg-weights + T14 async x-prefetch.
// grid = B*H (1024), 256 threads. LDS 40,960 B. tfwM output is bf16.
// ---------------------------------------------------------------------------
__device__ __forceinline__ float4 load_xtile(const float* __restrict__ x,
    int b, int h, int w0, int lane, int wv, int r)
{
    const int q = lane & 3, wg = lane >> 2;
    const int cb = 16 * r + 4 * wv;
    return *(const float4*)&x[((size_t)(b * 64 + cb + q) * 256 + h) * 256 + w0 + wg * 4];
}

__global__ __launch_bounds__(256) void k_wbtfw(
    const float* __restrict__ x,
    const unsigned short* __restrict__ wT0, const float* __restrict__ b0,
    const unsigned short* __restrict__ wT1, const float* __restrict__ b1,
    const unsigned short* __restrict__ wT2, const float* __restrict__ b2,
    unsigned short* __restrict__ wb_bf, unsigned short* __restrict__ tfwM)
{
    __shared__ __align__(16) unsigned short smem[20480];  // 40,960 B
    unsigned short* sA   = smem;              // [64][96] swizzled
    unsigned short* sB   = smem + 6144;       // [64][96] swizzled
    unsigned short* sXt  = smem + 12288;      // [64][64] swizzled x rows
    unsigned short* sWBt = smem + 16384;      // [64][64] swizzled wb^T rows

    const int bh = blockIdx.x;
    const int b = bh >> 8, h = bh & 255;
    const int t = threadIdx.x;
    const int lane = t & 63, wv = t >> 6;
    const int arow = lane & 15, g = lane >> 4;
    const int crow = 16 * wv + g * 4;
    const int sx7 = arow & 7;
    const f32x4 zero = {0.f, 0.f, 0.f, 0.f};

    // weights -> registers (once per block; L2-resident)
    const int wrow = 16 * wv + arow;
    bf16x8 w0f[3], w1f[2], w2f[2];
#pragma unroll
    for (int kc = 0; kc < 3; ++kc)
        w0f[kc] = *(const bf16x8*)&wT0[wrow * 96 + (kc * 4 + g) * 8];
#pragma unroll
    for (int kc = 0; kc < 2; ++kc) {
        w1f[kc] = *(const bf16x8*)&wT1[wrow * 64 + (kc * 4 + g) * 8];
        w2f[kc] = *(const bf16x8*)&wT2[wrow * 64 + (kc * 4 + g) * 8];
    }
    const float4 bv0 = *(const float4*)&b0[crow];
    const float4 bv1 = *(const float4*)&b1[crow];
    const float4 bv2 = *(const float4*)&b2[crow];

    f32x4 atf[4] = {zero, zero, zero, zero};   // tfw accumulator across tiles

    // T14 prefetch: tile 0 loads issued before the loop
    float4 xv[4];
#pragma unroll
    for (int r = 0; r < 4; ++r) xv[r] = load_xtile(x, b, h, 0, lane, wv, r);

    for (int wq = 0; wq < 4; ++wq) {
        const int w0 = wq * 64;
        __syncthreads();   // protect buffers from prior tile's readers
        // stage from prefetched regs: sXt[c][w] + sA[px][c], both swizzled
        {
            const int q = lane & 3, wg = lane >> 2;
#pragma unroll
            for (int r = 0; r < 4; ++r) {
                const int cb = 16 * r + 4 * wv;
                const int c = cb + q;
                const float4 v = xv[r];
                ushort4 ux;
                ux.x = f2b(v.x); ux.y = f2b(v.y); ux.z = f2b(v.z); ux.w = f2b(v.w);
                const int chx = (wg >> 1) ^ (c & 7);
                *(ushort4*)&sXt[c * 64 + chx * 8 + 4 * (wg & 1)] = ux;
                const ushort4 u = butterfly_xT(v, q);
                const int row = wg * 4 + q;   // == lane
                const int cha = (cb >> 3) ^ (row & 7);
                *(ushort4*)&sA[row * 96 + cha * 8 + (cb & 7)] = u;
            }
        }
        if (t < 64) {
            const uint4 z = {0, 0, 0, 0};
#pragma unroll
            for (int j = 0; j < 4; ++j)
                *(uint4*)&sA[t * 96 + (8 + (j ^ (t & 3))) * 8] = z;
            sA[t * 96 + (8 + (t & 3)) * 8] = f2b((float)(w0 + t) * (2.0f / 255.0f) - 1.0f);
        }
        // T14: issue next tile's loads now; they land during L0-L2
        const int w0n = ((wq + 1) & 3) * 64;
        float4 xn[4];
#pragma unroll
        for (int r = 0; r < 4; ++r) xn[r] = load_xtile(x, b, h, w0n, lane, wv, r);
        __syncthreads();
        mfma_layer_r<true, 3>(w0f, sA, sB, bv0, arow, g, wv);
        __syncthreads();
        mfma_layer_r<true, 2>(w1f, sB, sA, bv1, arow, g, wv);
        __syncthreads();
        // layer 2 inline: regs -> sB [px][o] and sWBt [o][px], swizzled
        {
            f32x4 acc[4] = {zero, zero, zero, zero};
#pragma unroll
            for (int kc = 0; kc < 2; ++kc) {
                const int ch = (kc * 4 + g) ^ sx7;
#pragma unroll
                for (int nt = 0; nt < 4; ++nt) {
                    const bf16x8 bb = *(const bf16x8*)&sA[(nt * 16 + arow) * 96 + ch * 8];
                    acc[nt] = __builtin_amdgcn_mfma_f32_16x16x32_bf16(w2f[kc], bb, acc[nt], 0, 0, 0);
                }
            }
            const int chw = (crow >> 3) ^ sx7;
#pragma unroll
            for (int nt = 0; nt < 4; ++nt) {
                const int px = nt * 16 + arow;
                ushort4 u;
                u.x = f2b(acc[nt][0] + bv2.x);
                u.y = f2b(acc[nt][1] + bv2.y);
                u.z = f2b(acc[nt][2] + bv2.z);
                u.w = f2b(acc[nt][3] + bv2.w);
                *(ushort4*)&sB[px * 96 + chw * 8 + (crow & 7)] = u;
                const int ph = px >> 3, pl = px & 7;
                sWBt[(crow + 0) * 64 + ((ph ^ ((crow + 0) & 7)) << 3) + pl] = u.x;
                sWBt[(crow + 1) * 64 + ((ph ^ ((crow + 1) & 7)) << 3) + pl] = u.y;
                sWBt[(crow + 2) * 64 + ((ph ^ ((crow + 2) & 7)) << 3) + pl] = u.z;
                sWBt[(crow + 3) * 64 + ((ph ^ ((crow + 3) & 7)) << 3) + pl] = u.w;
            }
        }
        __syncthreads();
        // wb_bf coalesced write (swizzled read) + tfw partial MFMA
        const size_t pixbase = (size_t)(b * 256 + h) * 256 + w0;
#pragma unroll
        for (int r = 0; r < 2; ++r) {
            const int idx = r * 256 + t;
            const int px = idx >> 3, f = idx & 7;
            *(uint4*)&wb_bf[(pixbase + px) * 64 + f * 8] =
                *(const uint4*)&sB[px * 96 + ((f ^ (px & 7)) << 3)];
        }
#pragma unroll
        for (int kc = 0; kc < 2; ++kc) {
            const int ch = (kc * 4 + g) ^ sx7;
            const bf16x8 a = *(const bf16x8*)&sWBt[(16 * wv + arow) * 64 + ch * 8];
#pragma unroll
            for (int nt = 0; nt < 4; ++nt) {
                const bf16x8 bb = *(const bf16x8*)&sXt[(nt * 16 + arow) * 64 + ch * 8];
                atf[nt] = __builtin_amdgcn_mfma_f32_16x16x32_bf16(a, bb, atf[nt], 0, 0, 0);
            }
        }
        // hand prefetched regs to next iteration
#pragma unroll
        for (int r = 0; r < 4; ++r) xv[r] = xn[r];
    }

    // epilogue: scatter D[mo][c] -> f32 LDS [mo][68], then bf16 tfwM write
    __syncthreads();
    float* sF = (float*)smem;   // 17,408 B fits in sA+sB region (24,576 B)
#pragma unroll
    for (int nt = 0; nt < 4; ++nt) {
        const int c = nt * 16 + arow;
#pragma unroll
        for (int j = 0; j < 4; ++j)
            sF[(crow + j) * 68 + c] = atf[nt][j];
    }
    __syncthreads();
#pragma unroll
    for (int r = 0; r < 4; ++r) {
        const int idx = r * 256 + t;
        const int m = idx >> 5, gg = idx & 31;
        ushort4 u;
        u.x = f2b(sF[m * 68 + gg * 2]);
        u.y = f2b(sF[(m + 32) * 68 + gg * 2]);
        u.z = f2b(sF[m * 68 + gg * 2 + 1]);
        u.w = f2b(sF[(m + 32) * 68 + gg * 2 + 1]);
        *(ushort4*)&tfwM[((size_t)(b * 32 + m) * 256 + h) * 128 + gg * 4] = u;
    }
}

// K3: hb basis, reg-weights + swizzled tiles, bf16 tfwM input. grid = B*M2*4.
__global__ __launch_bounds__(256) void k_hb_mlp3(
    const unsigned short* __restrict__ tfwM,
    const unsigned short* __restrict__ hT0, const float* __restrict__ b0,
    const unsigned short* __restrict__ hT1, const float* __restrict__ b1,
    const unsigned short* __restrict__ hT2, const float* __restrict__ b2,
    unsigned short* __restrict__ hb_bf)
{
    __shared__ __align__(16) unsigned short sA[64 * 96];
    __shared__ __align__(16) unsigned short sB[64 * 96];
    const int blk = blockIdx.x;
    const int bm = blk >> 2, hq = blk & 3;
    const int h0 = hq * 64;
    const int t = threadIdx.x;
    const int lane = t & 63, wv = t >> 6;
    const int arow = lane & 15, g = lane >> 4;
    const int crow = 16 * wv + g * 4;

    const int wrow = 16 * wv + arow;
    bf16x8 h0f[3], h1f[2], h2f[2];
#pragma unroll
    for (int kc = 0; kc < 3; ++kc)
        h0f[kc] = *(const bf16x8*)&hT0[wrow * 96 + (kc * 4 + g) * 8];
#pragma unroll
    for (int kc = 0; kc < 2; ++kc) {
        h1f[kc] = *(const bf16x8*)&hT1[wrow * 64 + (kc * 4 + g) * 8];
        h2f[kc] = *(const bf16x8*)&hT2[wrow * 64 + (kc * 4 + g) * 8];
    }
    const float4 bv0 = *(const float4*)&b0[crow];
    const float4 bv1 = *(const float4*)&b1[crow];
    const float4 bv2 = *(const float4*)&b2[crow];

    // stage tfw real parts -> sA[p][c] swizzled (extract even bf16 lanes)
#pragma unroll
    for (int r = 0; r < 4; ++r) {
        const int idx = r * 256 + t;
        const int p = idx >> 4, f = idx & 15;
        const uint4 raw = *(const uint4*)&tfwM[((size_t)(bm * 256 + h0 + p)) * 128 + f * 8];
        const unsigned short* s = (const unsigned short*)&raw;
        ushort4 u;
        u.x = s[0]; u.y = s[2]; u.z = s[4]; u.w = s[6];
        const int ch = (f >> 1) ^ (p & 7);
        *(ushort4*)&sA[p * 96 + ch * 8 + 4 * (f & 1)] = u;
    }
    if (t < 64) {
        const uint4 z = {0, 0, 0, 0};
#pragma unroll
        for (int j = 0; j < 4; ++j)
            *(uint4*)&sA[t * 96 + (8 + (j ^ (t & 3))) * 8] = z;
        sA[t * 96 + (8 + (t & 3)) * 8] = f2b((float)(h0 + t) * (2.0f / 255.0f) - 1.0f);
    }
    __syncthreads();
    mfma_layer_r<true, 3>(h0f, sA, sB, bv0, arow, g, wv);
    __syncthreads();
    mfma_layer_r<true, 2>(h1f, sB, sA, bv1, arow, g, wv);
    __syncthreads();
    mfma_layer_r<false, 2>(h2f, sA, sB, bv2, arow, g, wv);
    __syncthreads();

    const size_t pixbase = (size_t)bm * 256 + h0;
#pragma unroll
    for (int r = 0; r < 2; ++r) {
        const int idx = r * 256 + t;
        const int px = idx >> 3, f = idx & 7;
        *(uint4*)&hb_bf[(pixbase + px) * 64 + f * 8] =
            *(const uint4*)&sB[px * 96 + ((f ^ (px & 7)) << 3)];
    }
}

// K4: tfhw partials, bf16 tfwM input. grid = 1024: (bm, chalf, hq).
__global__ __launch_bounds__(256) void k_tfhw3(
    const unsigned short* __restrict__ tfwM,
    const unsigned short* __restrict__ hb_bf,
    float* __restrict__ tfhw_p)
{
    __shared__ float hr[64 * 32];
    __shared__ float hi2[64 * 32];
    __shared__ float slab[32 * 64];
    const int blk = blockIdx.x;
    const int bm = blk >> 3, chalf = (blk >> 2) & 1, hq = blk & 3;
    const int b = bm >> 5, m = bm & 31;
    const int t = threadIdx.x;
#pragma unroll
    for (int r = 0; r < 2; ++r) {
        const int q = r * 256 + t;
        const int hl = q >> 3, f = q & 7;
        const uint4 raw = *(const uint4*)&hb_bf[((size_t)bm * 256 + hq * 64 + hl) * 64 + f * 8];
        const unsigned short* us = (const unsigned short*)&raw;
        float v[8];
#pragma unroll
        for (int j = 0; j < 8; ++j) v[j] = b2f(us[j]);
        float* dst = (f < 4) ? &hr[hl * 32 + f * 8] : &hi2[hl * 32 + (f - 4) * 8];
        float4 lo; lo.x = v[0]; lo.y = v[1]; lo.z = v[2]; lo.w = v[3];
        float4 hi; hi.x = v[4]; hi.y = v[5]; hi.z = v[6]; hi.w = v[7];
        *(float4*)&dst[0] = lo;
        *(float4*)&dst[4] = hi;
    }
    const int k = t & 31, cq = t >> 5;
    float accr[4] = {0.f, 0.f, 0.f, 0.f}, acci[4] = {0.f, 0.f, 0.f, 0.f};
    const size_t tbase = (size_t)bm * 32768;
    for (int ht = 0; ht < 2; ++ht) {
        __syncthreads();
        {
            const int hl = t >> 3, f = t & 7;
            const uint4 raw = *(const uint4*)&tfwM[tbase + (size_t)(hq * 64 + ht * 32 + hl) * 128 + chalf * 64 + f * 8];
            const unsigned short* s = (const unsigned short*)&raw;
            float4 lo, hi;
            lo.x = b2f(s[0]); lo.y = b2f(s[1]); lo.z = b2f(s[2]); lo.w = b2f(s[3]);
            hi.x = b2f(s[4]); hi.y = b2f(s[5]); hi.z = b2f(s[6]); hi.w = b2f(s[7]);
            *(float4*)&slab[hl * 64 + f * 8] = lo;
            *(float4*)&slab[hl * 64 + f * 8 + 4] = hi;
        }
        __syncthreads();
#pragma unroll 8
        for (int hl = 0; hl < 32; ++hl) {
            const float hrv = hr[(ht * 32 + hl) * 32 + k];
            const float hiv = hi2[(ht * 32 + hl) * 32 + k];
            const float4 u0 = *(const float4*)&slab[hl * 64 + cq * 8];
            const float4 u1 = *(const float4*)&slab[hl * 64 + cq * 8 + 4];
            accr[0] = fmaf(u0.x, hrv, fmaf(-u0.y, hiv, accr[0]));
            acci[0] = fmaf(u0.x, hiv, fmaf( u0.y, hrv, acci[0]));
            accr[1] = fmaf(u0.z, hrv, fmaf(-u0.w, hiv, accr[1]));
            acci[1] = fmaf(u0.z, hiv, fmaf( u0.w, hrv, acci[1]));
            accr[2] = fmaf(u1.x, hrv, fmaf(-u1.y, hiv, accr[2]));
            acci[2] = fmaf(u1.x, hiv, fmaf( u1.y, hrv, acci[2]));
            accr[3] = fmaf(u1.z, hrv, fmaf(-u1.w, hiv, accr[3]));
            acci[3] = fmaf(u1.z, hiv, fmaf( u1.w, hrv, acci[3]));
        }
    }
    float* tp = tfhw_p + (size_t)hq * 524288;
#pragma unroll
    for (int i = 0; i < 4; ++i) {
        const int c = chalf * 32 + cq * 4 + i;
        const size_t po = ((size_t)(b * 64 + c) * 32 + k) * 32 + m;
        tp[po] = accr[i];
        tp[262144 + po] = acci[i];
    }
}

// K5: proc partials. grid = 512: (o, kq, chalf).
__global__ __launch_bounds__(256) void k_proc2(
    const float* __restrict__ tfhw,
    const float* __restrict__ Wf_re, const float* __restrict__ Wf_im,
    float* __restrict__ proc_p)
{
    const int blk = blockIdx.x;
    const int o = blk >> 3, kq = (blk >> 1) & 3, chalf = blk & 1;
    const int t = threadIdx.x;
    const int mo = kq * 256 + t;
    const float* tre = tfhw;
    const float* tim = tfhw + 262144;
    float accr[4] = {0.f, 0.f, 0.f, 0.f}, acci[4] = {0.f, 0.f, 0.f, 0.f};
    for (int cc = 0; cc < 32; ++cc) {
        const int c = chalf * 32 + cc;
        const float wfr = Wf_re[(size_t)(c * 64 + o) * 1024 + mo];
        const float wfi = Wf_im[(size_t)(c * 64 + o) * 1024 + mo];
#pragma unroll
        for (int bb = 0; bb < 4; ++bb) {
            const float tr = tre[(size_t)(bb * 64 + c) * 1024 + mo];
            const float ti = tim[(size_t)(bb * 64 + c) * 1024 + mo];
            accr[bb] = fmaf(tr, wfr, fmaf(-ti, wfi, accr[bb]));
            acci[bb] = fmaf(tr, wfi, fmaf(ti, wfr, acci[bb]));
        }
    }
    float* pp = proc_p + (size_t)chalf * 524288;
#pragma unroll
    for (int bb = 0; bb < 4; ++bb) {
        pp[(size_t)(bb * 64 + o) * 1024 + mo] = accr[bb];
        pp[262144 + (size_t)(bb * 64 + o) * 1024 + mo] = acci[bb];
    }
}

// K6: recO bf16. grid = 1024: (bm, hq8). Coalesced procT reads.
__global__ __launch_bounds__(256) void k_rec4(
    const float* __restrict__ procT,
    const unsigned short* __restrict__ hb_bf,
    unsigned short* __restrict__ recO)
{
    __shared__ float lhr[32 * 32];
    __shared__ float lhi[32 * 32];
    const int blk = blockIdx.x;
    const int bm = blk >> 3, hq = blk & 7;
    const int b = bm >> 5, m = bm & 31;
    const int t = threadIdx.x;
    {
        const int hl = t >> 3, f = t & 7;
        const uint4 raw = *(const uint4*)&hb_bf[((size_t)bm * 256 + hq * 32 + hl) * 64 + f * 8];
        const unsigned short* us = (const unsigned short*)&raw;
        float v[8];
#pragma unroll
        for (int j = 0; j < 8; ++j) v[j] = b2f(us[j]);
        float* dst = (f < 4) ? &lhr[hl * 32 + f * 8] : &lhi[hl * 32 + (f - 4) * 8];
        float4 lo; lo.x = v[0]; lo.y = v[1]; lo.z = v[2]; lo.w = v[3];
        float4 hi; hi.x = v[4]; hi.y = v[5]; hi.z = v[6]; hi.w = v[7];
        *(float4*)&dst[0] = lo;
        *(float4*)&dst[4] = hi;
    }
    const int o = t & 63, hg = t >> 6;
    const float* pr = procT + (size_t)(b * 32 + m) * 2048 + o;
    const float* pi = pr + 262144;
    float Pr[32], Pi[32];
#pragma unroll
    for (int k = 0; k < 32; ++k) {
        Pr[k] = pr[k * 64];
        Pi[k] = pi[k * 64];
    }
    __syncthreads();
    for (int hh = 0; hh < 8; ++hh) {
        const int hl = hg * 8 + hh;
        float ar = 0.f, ai = 0.f;
#pragma unroll
        for (int k4 = 0; k4 < 8; ++k4) {
            const float4 hr4 = *(const float4*)&lhr[hl * 32 + k4 * 4];
            const float4 hi4 = *(const float4*)&lhi[hl * 32 + k4 * 4];
            ar = fmaf(Pr[k4*4+0], hr4.x, fmaf(Pi[k4*4+0], hi4.x, ar));
            ai = fmaf(Pi[k4*4+0], hr4.x, fmaf(-Pr[k4*4+0], hi4.x, ai));
            ar = fmaf(Pr[k4*4+1], hr4.y, fmaf(Pi[k4*4+1], hi4.y, ar));
            ai = fmaf(Pi[k4*4+1], hr4.y, fmaf(-Pr[k4*4+1], hi4.y, ai));
            ar = fmaf(Pr[k4*4+2], hr4.z, fmaf(Pi[k4*4+2], hi4.z, ar));
            ai = fmaf(Pi[k4*4+2], hr4.z, fmaf(-Pr[k4*4+2], hi4.z, ai));
            ar = fmaf(Pr[k4*4+3], hr4.w, fmaf(Pi[k4*4+3], hi4.w, ar));
            ai = fmaf(Pi[k4*4+3], hr4.w, fmaf(-Pr[k4*4+3], hi4.w, ai));
        }
        const int h = hq * 32 + hl;
        const size_t rb = ((size_t)(b * 256 + h) * 64 + o) * 64;
        recO[rb + m]      = f2b(ar);
        recO[rb + 32 + m] = f2b(ai);
    }
}

// K7: MFMA fused final. grid = B*H*4. (round-10 version: x fp32 + butterfly)
__global__ __launch_bounds__(256) void k_final4(
    const float* __restrict__ x,
    const unsigned short* __restrict__ wb_bf,
    const unsigned short* __restrict__ recO,
    const float* __restrict__ mw, const float* __restrict__ mb,
    const float* __restrict__ scw, const float* __restrict__ scb,
    float* __restrict__ out)
{
    constexpr int LD = 72;
    __shared__ __align__(16) unsigned short sWb[64 * LD];
    __shared__ __align__(16) unsigned short sR [64 * LD];
    __shared__ __align__(16) unsigned short sX [64 * LD];
    __shared__ __align__(16) unsigned short sS [64 * LD];
    const int blk = blockIdx.x;
    const int b = blk >> 10, h = (blk >> 2) & 255, wq = blk & 3;
    const int w0 = wq * 64;
    const int t = threadIdx.x;
    const int lane = t & 63, wv = t >> 6;
    const size_t pixbase = (size_t)(b * 256 + h) * 256 + w0;

#pragma unroll
    for (int r = 0; r < 2; ++r) {
        const int idx = r * 256 + t;
        const int px = idx >> 3, f = idx & 7;
        *(uint4*)&sWb[px * LD + f * 8] = *(const uint4*)&wb_bf[(pixbase + px) * 64 + f * 8];
    }
    const size_t recbase = (size_t)(b * 256 + h) * 4096;
#pragma unroll
    for (int r = 0; r < 2; ++r) {
        const int idx = r * 256 + t;
        const int o = idx >> 3, f = idx & 7;
        *(uint4*)&sR[o * LD + f * 8] = *(const uint4*)&recO[recbase + (size_t)o * 64 + f * 8];
    }
    stage_xT(x, sX, b, h, w0, t, LD);
    __syncthreads();

    const int arow = lane & 15;
    const int koff = (lane >> 4) * 8;
    const f32x4 zero = {0.f, 0.f, 0.f, 0.f};

    f32x4 accA[4] = {zero, zero, zero, zero};
#pragma unroll
    for (int kc = 0; kc < 2; ++kc) {
        const bf16x8 a = *(const bf16x8*)&sR[(16 * wv + arow) * LD + kc * 32 + koff];
#pragma unroll
        for (int nt = 0; nt < 4; ++nt) {
            const bf16x8 bb = *(const bf16x8*)&sWb[(nt * 16 + arow) * LD + kc * 32 + koff];
            accA[nt] = __builtin_amdgcn_mfma_f32_16x16x32_bf16(a, bb, accA[nt], 0, 0, 0);
        }
    }
    __syncthreads();

    const int crow = 16 * wv + (lane >> 4) * 4;
#pragma unroll
    for (int nt = 0; nt < 4; ++nt) {
        const int px = nt * 16 + arow;
#pragma unroll
        for (int j = 0; j < 4; ++j)
            sS[px * LD + crow + j] = f2b(accA[nt][j] * (1.0f / 65536.0f));
    }
#pragma unroll
    for (int r = 0; r < 4; ++r) {
        const int idx = r * 256 + t;
        const int o = idx >> 4, cq = idx & 15;
        const float4 v1 = *(const float4*)&mw[o * 64 + cq * 4];
        ushort4 u1;
        u1.x = f2b(v1.x); u1.y = f2b(v1.y); u1.z = f2b(v1.z); u1.w = f2b(v1.w);
        *(ushort4*)&sWb[o * LD + cq * 4] = u1;
        const float4 v2 = *(const float4*)&scw[o * 64 + cq * 4];
        ushort4 u2;
        u2.x = f2b(v2.x); u2.y = f2b(v2.y); u2.z = f2b(v2.z); u2.w = f2b(v2.w);
        *(ushort4*)&sR[o * LD + cq * 4] = u2;
    }
    __syncthreads();

    f32x4 accB[4] = {zero, zero, zero, zero};
    f32x4 accC[4] = {zero, zero, zero, zero};
#pragma unroll
    for (int kc = 0; kc < 2; ++kc) {
        const bf16x8 am = *(const bf16x8*)&sWb[(16 * wv + arow) * LD + kc * 32 + koff];
        const bf16x8 as = *(const bf16x8*)&sR [(16 * wv + arow) * LD + kc * 32 + koff];
#pragma unroll
        for (int nt = 0; nt < 4; ++nt) {
            const bf16x8 bs = *(const bf16x8*)&sS[(nt * 16 + arow) * LD + kc * 32 + koff];
            const bf16x8 bx = *(const bf16x8*)&sX[(nt * 16 + arow) * LD + kc * 32 + koff];
            accB[nt] = __builtin_amdgcn_mfma_f32_16x16x32_bf16(am, bs, accB[nt], 0, 0, 0);
            accC[nt] = __builtin_amdgcn_mfma_f32_16x16x32_bf16(as, bx, accC[nt], 0, 0, 0);
        }
    }

#pragma unroll
    for (int nt = 0; nt < 4; ++nt) {
        const int px = nt * 16 + arow;
#pragma unroll
        for (int j = 0; j < 4; ++j) {
            const int o = crow + j;
            const float y = gelu_f(accB[nt][j] + mb[o]);
            const float z = y + accC[nt][j] + scb[o];
            out[((size_t)(b * 64 + o) * 256 + h) * 256 + w0 + px] = gelu_f(z);
        }
    }
}

extern "C" void kernel_launch(void* const* d_in, const int* in_sizes, int n_in,
                              void* d_out, int out_size, void* d_ws, size_t ws_size,
                              hipStream_t stream) {
    const float* x    = (const float*)d_in[0];
    const float* wW0  = (const float*)d_in[1];
    const float* wb0  = (const float*)d_in[2];
    const float* wW1  = (const float*)d_in[3];
    const float* wb1  = (const float*)d_in[4];
    const float* wW2  = (const float*)d_in[5];
    const float* wb2  = (const float*)d_in[6];
    const float* hW0  = (const float*)d_in[7];
    const float* hb0  = (const float*)d_in[8];
    const float* hW1  = (const float*)d_in[9];
    const float* hb1  = (const float*)d_in[10];
    const float* hW2  = (const float*)d_in[11];
    const float* hb2  = (const float*)d_in[12];
    const float* Wf_re = (const float*)d_in[13];
    const float* Wf_im = (const float*)d_in[14];
    const float* mw   = (const float*)d_in[15];
    const float* mbv  = (const float*)d_in[16];
    const float* scw  = (const float*)d_in[17];
    const float* scb  = (const float*)d_in[18];

    char* base = (char*)d_ws;
    unsigned short* wb_bf = (unsigned short*)(base + 0);            // 33,554,432
    unsigned short* tfwM  = (unsigned short*)(base + 33554432);     //  8,388,608 (bf16)
    unsigned short* hb_bf = (unsigned short*)(base + 41943040);     //  4,194,304
    float* tfhw_p = (float*)(base + 46137344);                      //  8,388,608 (4 parts)
    float* tfhw   = (float*)(base + 54525952);                      //  2,097,152 (re||im)
    float* proc_p = (float*)(base + 56623104);                      //  4,194,304 (2 parts)
    float* procT  = (float*)(base + 60817408);                      //  2,097,152 (re||im)
    unsigned short* recO = (unsigned short*)(base + 62914560);      //  8,388,608
    unsigned short* wT0 = (unsigned short*)(base + 71303168);       //     12,288
    unsigned short* wT1 = (unsigned short*)(base + 71315456);       //      8,192
    unsigned short* wT2 = (unsigned short*)(base + 71323648);
    unsigned short* hT0 = (unsigned short*)(base + 71331840);
    unsigned short* hT1 = (unsigned short*)(base + 71344128);
    unsigned short* hT2 = (unsigned short*)(base + 71352320);
    // total ~71.4 MB

    k_prep<<<1, 256, 0, stream>>>(wW0, wW1, wW2, hW0, hW1, hW2,
                                  wT0, wT1, wT2, hT0, hT1, hT2);
    k_wbtfw<<<1024, 256, 0, stream>>>(x, wT0, wb0, wT1, wb1, wT2, wb2,
                                      wb_bf, tfwM);
    k_hb_mlp3<<<512, 256, 0, stream>>>(tfwM, hT0, hb0, hT1, hb1, hT2, hb2, hb_bf);
    k_tfhw3<<<1024, 256, 0, stream>>>(tfwM, hb_bf, tfhw_p);
    k_psum<<<1024, 256, 0, stream>>>(tfhw_p, tfhw, 4, 524288);
    k_proc2<<<512, 256, 0, stream>>>(tfhw, Wf_re, Wf_im, proc_p);
    k_psum_procT<<<1024, 256, 0, stream>>>(proc_p, procT);
    k_rec4<<<1024, 256, 0, stream>>>(procT, hb_bf, recO);
    k_final4<<<4096, 256, 0, stream>>>(x, wb_bf, recO, mw, mbv, scw, scb,
                                       (float*)d_out);
}

// Round 13
// 176.472 us; speedup vs baseline: 1.0949x; 1.0208x over previous
//
#include <hip/hip_runtime.h>
#include <math.h>

// B=4, C=64, OUT=64, H=256, W=256, M1=32, M2=32, HID=64, COORD=65

typedef __attribute__((ext_vector_type(8))) short bf16x8;
typedef __attribute__((ext_vector_type(4))) float f32x4;

// Fast exact-erf GELU: Abramowitz-Stegun 7.1.26, |eps_erf| <= 1.5e-7.
__device__ __forceinline__ float gelu_f(float v) {
    const float u = v * 0.70710678118654752440f;
    const float xa = fabsf(u);
    const float t = __builtin_amdgcn_rcpf(fmaf(0.3275911f, xa, 1.0f));
    float p = fmaf(1.061405429f, t, -1.453152027f);
    p = fmaf(p, t, 1.421413741f);
    p = fmaf(p, t, -0.284496736f);
    p = fmaf(p, t, 0.254829592f);
    p *= t;
    const float e = __expf(-xa * xa);
    float erfv = fmaf(-p, e, 1.0f);
    erfv = (u < 0.0f) ? -erfv : erfv;
    return 0.5f * v * (1.0f + erfv);
}

__device__ __forceinline__ unsigned short f2b(float f) {
    union { float f; unsigned int u; } v; v.f = f;
    unsigned int u = v.u + 0x7FFFu + ((v.u >> 16) & 1u);   // RNE
    return (unsigned short)(u >> 16);
}
__device__ __forceinline__ float b2f(unsigned short b) {
    union { unsigned int u; float f; } v; v.u = ((unsigned int)b) << 16;
    return v.f;
}

// ---------------------------------------------------------------------------
// 4x4 butterfly transpose within 4-lane clusters (lane^1, lane^2).
// ---------------------------------------------------------------------------
__device__ __forceinline__ ushort4 butterfly_xT(const float4 v, int q) {
    const float bx = __shfl_xor(v.x, 1);
    const float by = __shfl_xor(v.y, 1);
    const float bz = __shfl_xor(v.z, 1);
    const float bw = __shfl_xor(v.w, 1);
    float4 s1;
    s1.x = ((q & 1) == 0) ? v.x : by;
    s1.y = ((q & 1) == 0) ? bx  : v.y;
    s1.z = ((q & 1) == 0) ? v.z : bw;
    s1.w = ((q & 1) == 0) ? bz  : v.w;
    const float cx = __shfl_xor(s1.x, 2);
    const float cy = __shfl_xor(s1.y, 2);
    const float cz = __shfl_xor(s1.z, 2);
    const float cw = __shfl_xor(s1.w, 2);
    float4 s2;
    s2.x = ((q & 2) == 0) ? s1.x : cz;
    s2.y = ((q & 2) == 0) ? s1.y : cw;
    s2.z = ((q & 2) == 0) ? cx   : s1.z;
    s2.w = ((q & 2) == 0) ? cy   : s1.w;
    ushort4 u;
    u.x = f2b(s2.x); u.y = f2b(s2.y); u.z = f2b(s2.z); u.w = f2b(s2.w);
    return u;
}

// Stage x^T into LDS [w_local][c] bf16 (stride LD, plain layout) for k_final4.
__device__ __forceinline__ void stage_xT(const float* __restrict__ x,
    unsigned short* __restrict__ sA, int b, int h, int w0, int t, int LD)
{
    const int lane = t & 63, wv = t >> 6;
    const int q = lane & 3, wg = lane >> 2;
#pragma unroll
    for (int r = 0; r < 4; ++r) {
        const int cb = (r * 4 + wv) * 4;
        const float4 v = *(const float4*)&x[((size_t)(b * 64 + cb + q) * 256 + h) * 256 + w0 + wg * 4];
        const ushort4 u = butterfly_xT(v, q);
        *(ushort4*)&sA[(wg * 4 + q) * LD + cb] = u;
    }
}

// ---------------------------------------------------------------------------
// K_prep: transpose + bf16-convert MLP weights. wT[o][k] = W[k][o]. K0 pad->96.
// ---------------------------------------------------------------------------
__global__ void k_prep(const float* __restrict__ wW0, const float* __restrict__ wW1,
                       const float* __restrict__ wW2,
                       const float* __restrict__ hW0, const float* __restrict__ hW1,
                       const float* __restrict__ hW2,
                       unsigned short* __restrict__ wT0, unsigned short* __restrict__ wT1,
                       unsigned short* __restrict__ wT2,
                       unsigned short* __restrict__ hT0, unsigned short* __restrict__ hT1,
                       unsigned short* __restrict__ hT2)
{
    const int t = threadIdx.x;
    for (int idx = t; idx < 64 * 96; idx += 256) {
        const int o = idx / 96, k = idx % 96;
        wT0[idx] = (k < 65) ? f2b(wW0[k * 64 + o]) : (unsigned short)0;
        hT0[idx] = (k < 65) ? f2b(hW0[k * 64 + o]) : (unsigned short)0;
    }
    for (int idx = t; idx < 4096; idx += 256) {
        const int o = idx >> 6, k = idx & 63;
        wT1[idx] = f2b(wW1[k * 64 + o]);
        wT2[idx] = f2b(wW2[k * 64 + o]);
        hT1[idx] = f2b(hW1[k * 64 + o]);
        hT2[idx] = f2b(hW2[k * 64 + o]);
    }
}

// generic partial-sum
__global__ __launch_bounds__(256) void k_psum(const float* __restrict__ src,
                                              float* __restrict__ dst,
                                              int nparts, int part_stride)
{
    const int i = (blockIdx.x * 256 + threadIdx.x) * 4;
    float4 acc = *(const float4*)&src[i];
    for (int p = 1; p < nparts; ++p) {
        const float4 v = *(const float4*)&src[(size_t)p * part_stride + i];
        acc.x += v.x; acc.y += v.y; acc.z += v.z; acc.w += v.w;
    }
    *(float4*)&dst[i] = acc;
}

// psum for proc + repack to procT[((b*32+m)*32+k)*64+o] (re || im at +262144).
__global__ __launch_bounds__(256) void k_psum_procT(const float* __restrict__ src,
                                                    float* __restrict__ dst)
{
    const int idx = blockIdx.x * 256 + threadIdx.x;
    const int o = idx & 63, k = (idx >> 6) & 31, m = (idx >> 11) & 31, b = idx >> 16;
    const size_t in = (size_t)(b * 64 + o) * 1024 + k * 32 + m;
    const float re = src[in] + src[524288 + in];
    const float im = src[262144 + in] + src[524288 + 262144 + in];
    dst[idx] = re;
    dst[262144 + idx] = im;
}

// ---------------------------------------------------------------------------
// Reg-weight MFMA MLP layer, swizzled stride-96 act tiles.
// Swizzle (per row): 16B-chunk ch<8 -> ch^(row&7); ch>=8 -> 8+((ch-8)^(row&3)).
// ---------------------------------------------------------------------------
template<bool GELU, int NKC>
__device__ __forceinline__ void mfma_layer_r(
    const bf16x8* __restrict__ wf,
    const unsigned short* __restrict__ sAct,
    unsigned short* __restrict__ dst,
    const float4 bv, int arow, int g, int wv)
{
    const int crow = 16 * wv + g * 4;
    const int sx7 = arow & 7, sx3 = arow & 3;
    const f32x4 zero = {0.f, 0.f, 0.f, 0.f};
    f32x4 acc[4] = {zero, zero, zero, zero};
#pragma unroll
    for (int kc = 0; kc < NKC; ++kc) {
        const int chraw = kc * 4 + g;
        const int ch = (chraw < 8) ? (chraw ^ sx7) : (8 + ((chraw - 8) ^ sx3));
#pragma unroll
        for (int nt = 0; nt < 4; ++nt) {
            const bf16x8 b = *(const bf16x8*)&sAct[(nt * 16 + arow) * 96 + ch * 8];
            acc[nt] = __builtin_amdgcn_mfma_f32_16x16x32_bf16(wf[kc], b, acc[nt], 0, 0, 0);
        }
    }
    const int chw = (crow >> 3) ^ sx7;
#pragma unroll
    for (int nt = 0; nt < 4; ++nt) {
        const int px = nt * 16 + arow;
        float v0 = acc[nt][0] + bv.x;
        float v1 = acc[nt][1] + bv.y;
        float v2 = acc[nt][2] + bv.z;
        float v3 = acc[nt][3] + bv.w;
        if (GELU) { v0 = gelu_f(v0); v1 = gelu_f(v1); v2 = gelu_f(v2); v3 = gelu_f(v3); }
        ushort4 u;
        u.x = f2b(v0); u.y = f2b(v1); u.z = f2b(v2); u.w = f2b(v3);
        *(ushort4*)&dst[px * 96 + chw * 8 + (crow & 7)] = u;
    }
}

// ---------------------------------------------------------------------------
// K1+K2 fused: wb MLP + tfw. Reg-weights + T14 async x-prefetch (no wrap).
// grid = B*H (1024), 256 threads. LDS 40,960 B. tfwM output is bf16.
// ---------------------------------------------------------------------------
__device__ __forceinline__ float4 load_xtile(const float* __restrict__ x,
    int b, int h, int w0, int lane, int wv, int r)
{
    const int q = lane & 3, wg = lane >> 2;
    const int cb = 16 * r + 4 * wv;
    return *(const float4*)&x[((size_t)(b * 64 + cb + q) * 256 + h) * 256 + w0 + wg * 4];
}

__global__ __launch_bounds__(256) void k_wbtfw(
    const float* __restrict__ x,
    const unsigned short* __restrict__ wT0, const float* __restrict__ b0,
    const unsigned short* __restrict__ wT1, const float* __restrict__ b1,
    const unsigned short* __restrict__ wT2, const float* __restrict__ b2,
    unsigned short* __restrict__ wb_bf, unsigned short* __restrict__ tfwM)
{
    __shared__ __align__(16) unsigned short smem[20480];  // 40,960 B
    unsigned short* sA   = smem;              // [64][96] swizzled
    unsigned short* sB   = smem + 6144;       // [64][96] swizzled
    unsigned short* sXt  = smem + 12288;      // [64][64] swizzled x rows
    unsigned short* sWBt = smem + 16384;      // [64][64] swizzled wb^T rows

    const int bh = blockIdx.x;
    const int b = bh >> 8, h = bh & 255;
    const int t = threadIdx.x;
    const int lane = t & 63, wv = t >> 6;
    const int arow = lane & 15, g = lane >> 4;
    const int crow = 16 * wv + g * 4;
    const int sx7 = arow & 7;
    const f32x4 zero = {0.f, 0.f, 0.f, 0.f};

    // weights -> registers (once per block; L2-resident)
    const int wrow = 16 * wv + arow;
    bf16x8 w0f[3], w1f[2], w2f[2];
#pragma unroll
    for (int kc = 0; kc < 3; ++kc)
        w0f[kc] = *(const bf16x8*)&wT0[wrow * 96 + (kc * 4 + g) * 8];
#pragma unroll
    for (int kc = 0; kc < 2; ++kc) {
        w1f[kc] = *(const bf16x8*)&wT1[wrow * 64 + (kc * 4 + g) * 8];
        w2f[kc] = *(const bf16x8*)&wT2[wrow * 64 + (kc * 4 + g) * 8];
    }
    const float4 bv0 = *(const float4*)&b0[crow];
    const float4 bv1 = *(const float4*)&b1[crow];
    const float4 bv2 = *(const float4*)&b2[crow];

    f32x4 atf[4] = {zero, zero, zero, zero};   // tfw accumulator across tiles

    // T14 prefetch: tile 0 loads issued before the loop
    float4 xv[4];
#pragma unroll
    for (int r = 0; r < 4; ++r) xv[r] = load_xtile(x, b, h, 0, lane, wv, r);

    for (int wq = 0; wq < 4; ++wq) {
        const int w0 = wq * 64;
        __syncthreads();   // protect buffers from prior tile's readers
        // stage from prefetched regs: sXt[c][w] + sA[px][c], both swizzled
        {
            const int q = lane & 3, wg = lane >> 2;
#pragma unroll
            for (int r = 0; r < 4; ++r) {
                const int cb = 16 * r + 4 * wv;
                const int c = cb + q;
                const float4 v = xv[r];
                ushort4 ux;
                ux.x = f2b(v.x); ux.y = f2b(v.y); ux.z = f2b(v.z); ux.w = f2b(v.w);
                const int chx = (wg >> 1) ^ (c & 7);
                *(ushort4*)&sXt[c * 64 + chx * 8 + 4 * (wg & 1)] = ux;
                const ushort4 u = butterfly_xT(v, q);
                const int row = wg * 4 + q;   // == lane
                const int cha = (cb >> 3) ^ (row & 7);
                *(ushort4*)&sA[row * 96 + cha * 8 + (cb & 7)] = u;
            }
        }
        if (t < 64) {
            const uint4 z = {0, 0, 0, 0};
#pragma unroll
            for (int j = 0; j < 4; ++j)
                *(uint4*)&sA[t * 96 + (8 + (j ^ (t & 3))) * 8] = z;
            sA[t * 96 + (8 + (t & 3)) * 8] = f2b((float)(w0 + t) * (2.0f / 255.0f) - 1.0f);
        }
        // T14: issue next tile's loads now (no wrap — avoids redundant fetch)
        float4 xn[4];
        if (wq < 3) {
            const int w0n = (wq + 1) * 64;
#pragma unroll
            for (int r = 0; r < 4; ++r) xn[r] = load_xtile(x, b, h, w0n, lane, wv, r);
        }
        __syncthreads();
        mfma_layer_r<true, 3>(w0f, sA, sB, bv0, arow, g, wv);
        __syncthreads();
        mfma_layer_r<true, 2>(w1f, sB, sA, bv1, arow, g, wv);
        __syncthreads();
        // layer 2 inline: regs -> sB [px][o] and sWBt [o][px], swizzled
        {
            f32x4 acc[4] = {zero, zero, zero, zero};
#pragma unroll
            for (int kc = 0; kc < 2; ++kc) {
                const int ch = (kc * 4 + g) ^ sx7;
#pragma unroll
                for (int nt = 0; nt < 4; ++nt) {
                    const bf16x8 bb = *(const bf16x8*)&sA[(nt * 16 + arow) * 96 + ch * 8];
                    acc[nt] = __builtin_amdgcn_mfma_f32_16x16x32_bf16(w2f[kc], bb, acc[nt], 0, 0, 0);
                }
            }
            const int chw = (crow >> 3) ^ sx7;
#pragma unroll
            for (int nt = 0; nt < 4; ++nt) {
                const int px = nt * 16 + arow;
                ushort4 u;
                u.x = f2b(acc[nt][0] + bv2.x);
                u.y = f2b(acc[nt][1] + bv2.y);
                u.z = f2b(acc[nt][2] + bv2.z);
                u.w = f2b(acc[nt][3] + bv2.w);
                *(ushort4*)&sB[px * 96 + chw * 8 + (crow & 7)] = u;
                const int ph = px >> 3, pl = px & 7;
                sWBt[(crow + 0) * 64 + ((ph ^ ((crow + 0) & 7)) << 3) + pl] = u.x;
                sWBt[(crow + 1) * 64 + ((ph ^ ((crow + 1) & 7)) << 3) + pl] = u.y;
                sWBt[(crow + 2) * 64 + ((ph ^ ((crow + 2) & 7)) << 3) + pl] = u.z;
                sWBt[(crow + 3) * 64 + ((ph ^ ((crow + 3) & 7)) << 3) + pl] = u.w;
            }
        }
        __syncthreads();
        // wb_bf coalesced write (swizzled read) + tfw partial MFMA
        const size_t pixbase = (size_t)(b * 256 + h) * 256 + w0;
#pragma unroll
        for (int r = 0; r < 2; ++r) {
            const int idx = r * 256 + t;
            const int px = idx >> 3, f = idx & 7;
            *(uint4*)&wb_bf[(pixbase + px) * 64 + f * 8] =
                *(const uint4*)&sB[px * 96 + ((f ^ (px & 7)) << 3)];
        }
#pragma unroll
        for (int kc = 0; kc < 2; ++kc) {
            const int ch = (kc * 4 + g) ^ sx7;
            const bf16x8 a = *(const bf16x8*)&sWBt[(16 * wv + arow) * 64 + ch * 8];
#pragma unroll
            for (int nt = 0; nt < 4; ++nt) {
                const bf16x8 bb = *(const bf16x8*)&sXt[(nt * 16 + arow) * 64 + ch * 8];
                atf[nt] = __builtin_amdgcn_mfma_f32_16x16x32_bf16(a, bb, atf[nt], 0, 0, 0);
            }
        }
        if (wq < 3) {
#pragma unroll
            for (int r = 0; r < 4; ++r) xv[r] = xn[r];
        }
    }

    // epilogue: scatter D[mo][c] -> f32 LDS [mo][68], then bf16 tfwM write
    __syncthreads();
    float* sF = (float*)smem;   // 17,408 B fits in sA+sB region (24,576 B)
#pragma unroll
    for (int nt = 0; nt < 4; ++nt) {
        const int c = nt * 16 + arow;
#pragma unroll
        for (int j = 0; j < 4; ++j)
            sF[(crow + j) * 68 + c] = atf[nt][j];
    }
    __syncthreads();
#pragma unroll
    for (int r = 0; r < 4; ++r) {
        const int idx = r * 256 + t;
        const int m = idx >> 5, gg = idx & 31;
        ushort4 u;
        u.x = f2b(sF[m * 68 + gg * 2]);
        u.y = f2b(sF[(m + 32) * 68 + gg * 2]);
        u.z = f2b(sF[m * 68 + gg * 2 + 1]);
        u.w = f2b(sF[(m + 32) * 68 + gg * 2 + 1]);
        *(ushort4*)&tfwM[((size_t)(b * 32 + m) * 256 + h) * 128 + gg * 4] = u;
    }
}

// ---------------------------------------------------------------------------
// K3+K4 fused: hb MLP + tfhw partials. grid = 512: (bm, hq). LDS 28,672 B.
// hb stays in LDS (sB) for the tfhw contraction; tfw slab overlays sA.
// ---------------------------------------------------------------------------
__global__ __launch_bounds__(256) void k_hbtfhw(
    const unsigned short* __restrict__ tfwM,
    const unsigned short* __restrict__ hT0, const float* __restrict__ b0,
    const unsigned short* __restrict__ hT1, const float* __restrict__ b1,
    const unsigned short* __restrict__ hT2, const float* __restrict__ b2,
    unsigned short* __restrict__ hb_bf, float* __restrict__ tfhw_p)
{
    __shared__ __align__(16) unsigned short smem[14336];  // 28,672 B
    unsigned short* sB = smem;             // [64][96] swizzled (hb final)
    unsigned short* sA = smem + 6144;      // [64][96] MLP ping (overlaid by slab)
    float* slab = (float*)(smem + 6144);   // [32][128] fp32, 16 KB

    const int blk = blockIdx.x;
    const int bm = blk >> 2, hq = blk & 3;
    const int b = bm >> 5, m = bm & 31;
    const int h0 = hq * 64;
    const int t = threadIdx.x;
    const int lane = t & 63, wv = t >> 6;
    const int arow = lane & 15, g = lane >> 4;
    const int crow = 16 * wv + g * 4;

    const int wrow = 16 * wv + arow;
    bf16x8 h0f[3], h1f[2], h2f[2];
#pragma unroll
    for (int kc = 0; kc < 3; ++kc)
        h0f[kc] = *(const bf16x8*)&hT0[wrow * 96 + (kc * 4 + g) * 8];
#pragma unroll
    for (int kc = 0; kc < 2; ++kc) {
        h1f[kc] = *(const bf16x8*)&hT1[wrow * 64 + (kc * 4 + g) * 8];
        h2f[kc] = *(const bf16x8*)&hT2[wrow * 64 + (kc * 4 + g) * 8];
    }
    const float4 bv0 = *(const float4*)&b0[crow];
    const float4 bv1 = *(const float4*)&b1[crow];
    const float4 bv2 = *(const float4*)&b2[crow];

    // stage tfw real parts -> sA[p][c] swizzled (even bf16 lanes)
#pragma unroll
    for (int r = 0; r < 4; ++r) {
        const int idx = r * 256 + t;
        const int p = idx >> 4, f = idx & 15;
        const uint4 raw = *(const uint4*)&tfwM[((size_t)(bm * 256 + h0 + p)) * 128 + f * 8];
        const unsigned short* s = (const unsigned short*)&raw;
        ushort4 u;
        u.x = s[0]; u.y = s[2]; u.z = s[4]; u.w = s[6];
        const int ch = (f >> 1) ^ (p & 7);
        *(ushort4*)&sA[p * 96 + ch * 8 + 4 * (f & 1)] = u;
    }
    if (t < 64) {
        const uint4 z = {0, 0, 0, 0};
#pragma unroll
        for (int j = 0; j < 4; ++j)
            *(uint4*)&sA[t * 96 + (8 + (j ^ (t & 3))) * 8] = z;
        sA[t * 96 + (8 + (t & 3)) * 8] = f2b((float)(h0 + t) * (2.0f / 255.0f) - 1.0f);
    }
    __syncthreads();
    mfma_layer_r<true, 3>(h0f, sA, sB, bv0, arow, g, wv);
    __syncthreads();
    mfma_layer_r<true, 2>(h1f, sB, sA, bv1, arow, g, wv);
    __syncthreads();
    mfma_layer_r<false, 2>(h2f, sA, sB, bv2, arow, g, wv);
    __syncthreads();   // sA readers done -> slab may overlay sA

    // hb_bf coalesced write from sB
    const size_t pixbase = (size_t)bm * 256 + h0;
#pragma unroll
    for (int r = 0; r < 2; ++r) {
        const int idx = r * 256 + t;
        const int px = idx >> 3, f = idx & 7;
        *(uint4*)&hb_bf[(pixbase + px) * 64 + f * 8] =
            *(const uint4*)&sB[px * 96 + ((f ^ (px & 7)) << 3)];
    }

    // tfhw: acc[c] += tfw[h][c] * hb[h][k]  (complex), hb read from sB in LDS
    const int k = t & 31, cq = t >> 5;
    float accr[8], acci[8];
#pragma unroll
    for (int i = 0; i < 8; ++i) { accr[i] = 0.f; acci[i] = 0.f; }
    const size_t tbase = (size_t)bm * 32768;
    for (int ht = 0; ht < 2; ++ht) {
        __syncthreads();
        // stage slab[32][128] fp32 from tfwM rows h0+ht*32..+31
#pragma unroll
        for (int r = 0; r < 2; ++r) {
            const int idx = r * 256 + t;
            const int hl = idx >> 4, f = idx & 15;
            const uint4 raw = *(const uint4*)&tfwM[tbase + (size_t)(h0 + ht * 32 + hl) * 128 + f * 8];
            const unsigned short* s = (const unsigned short*)&raw;
            float4 lo, hi;
            lo.x = b2f(s[0]); lo.y = b2f(s[1]); lo.z = b2f(s[2]); lo.w = b2f(s[3]);
            hi.x = b2f(s[4]); hi.y = b2f(s[5]); hi.z = b2f(s[6]); hi.w = b2f(s[7]);
            *(float4*)&slab[hl * 128 + f * 8] = lo;
            *(float4*)&slab[hl * 128 + f * 8 + 4] = hi;
        }
        __syncthreads();
#pragma unroll 8
        for (int hl = 0; hl < 32; ++hl) {
            const int hrow = ht * 32 + hl;
            const float hrv = b2f(sB[hrow * 96 + (((k >> 3) ^ (hrow & 7)) << 3) + (k & 7)]);
            const float hiv = b2f(sB[hrow * 96 + ((((32 + k) >> 3) ^ (hrow & 7)) << 3) + (k & 7)]);
#pragma unroll
            for (int i2 = 0; i2 < 4; ++i2) {
                const float4 u = *(const float4*)&slab[hl * 128 + cq * 16 + i2 * 4];
                accr[i2 * 2]     = fmaf(u.x, hrv, fmaf(-u.y, hiv, accr[i2 * 2]));
                acci[i2 * 2]     = fmaf(u.x, hiv, fmaf( u.y, hrv, acci[i2 * 2]));
                accr[i2 * 2 + 1] = fmaf(u.z, hrv, fmaf(-u.w, hiv, accr[i2 * 2 + 1]));
                acci[i2 * 2 + 1] = fmaf(u.z, hiv, fmaf( u.w, hrv, acci[i2 * 2 + 1]));
            }
        }
    }
    float* tp = tfhw_p + (size_t)hq * 524288;
#pragma unroll
    for (int i = 0; i < 8; ++i) {
        const int c = cq * 8 + i;
        const size_t po = ((size_t)(b * 64 + c) * 32 + k) * 32 + m;
        tp[po] = accr[i];
        tp[262144 + po] = acci[i];
    }
}

// K5: proc partials. grid = 512: (o, kq, chalf).
__global__ __launch_bounds__(256) void k_proc2(
    const float* __restrict__ tfhw,
    const float* __restrict__ Wf_re, const float* __restrict__ Wf_im,
    float* __restrict__ proc_p)
{
    const int blk = blockIdx.x;
    const int o = blk >> 3, kq = (blk >> 1) & 3, chalf = blk & 1;
    const int t = threadIdx.x;
    const int mo = kq * 256 + t;
    const float* tre = tfhw;
    const float* tim = tfhw + 262144;
    float accr[4] = {0.f, 0.f, 0.f, 0.f}, acci[4] = {0.f, 0.f, 0.f, 0.f};
    for (int cc = 0; cc < 32; ++cc) {
        const int c = chalf * 32 + cc;
        const float wfr = Wf_re[(size_t)(c * 64 + o) * 1024 + mo];
        const float wfi = Wf_im[(size_t)(c * 64 + o) * 1024 + mo];
#pragma unroll
        for (int bb = 0; bb < 4; ++bb) {
            const float tr = tre[(size_t)(bb * 64 + c) * 1024 + mo];
            const float ti = tim[(size_t)(bb * 64 + c) * 1024 + mo];
            accr[bb] = fmaf(tr, wfr, fmaf(-ti, wfi, accr[bb]));
            acci[bb] = fmaf(tr, wfi, fmaf(ti, wfr, acci[bb]));
        }
    }
    float* pp = proc_p + (size_t)chalf * 524288;
#pragma unroll
    for (int bb = 0; bb < 4; ++bb) {
        pp[(size_t)(bb * 64 + o) * 1024 + mo] = accr[bb];
        pp[262144 + (size_t)(bb * 64 + o) * 1024 + mo] = acci[bb];
    }
}

// K6: recO bf16. grid = 1024: (bm, hq8). Coalesced procT reads.
__global__ __launch_bounds__(256) void k_rec4(
    const float* __restrict__ procT,
    const unsigned short* __restrict__ hb_bf,
    unsigned short* __restrict__ recO)
{
    __shared__ float lhr[32 * 32];
    __shared__ float lhi[32 * 32];
    const int blk = blockIdx.x;
    const int bm = blk >> 3, hq = blk & 7;
    const int b = bm >> 5, m = bm & 31;
    const int t = threadIdx.x;
    {
        const int hl = t >> 3, f = t & 7;
        const uint4 raw = *(const uint4*)&hb_bf[((size_t)bm * 256 + hq * 32 + hl) * 64 + f * 8];
        const unsigned short* us = (const unsigned short*)&raw;
        float v[8];
#pragma unroll
        for (int j = 0; j < 8; ++j) v[j] = b2f(us[j]);
        float* dst = (f < 4) ? &lhr[hl * 32 + f * 8] : &lhi[hl * 32 + (f - 4) * 8];
        float4 lo; lo.x = v[0]; lo.y = v[1]; lo.z = v[2]; lo.w = v[3];
        float4 hi; hi.x = v[4]; hi.y = v[5]; hi.z = v[6]; hi.w = v[7];
        *(float4*)&dst[0] = lo;
        *(float4*)&dst[4] = hi;
    }
    const int o = t & 63, hg = t >> 6;
    const float* pr = procT + (size_t)(b * 32 + m) * 2048 + o;
    const float* pi = pr + 262144;
    float Pr[32], Pi[32];
#pragma unroll
    for (int k = 0; k < 32; ++k) {
        Pr[k] = pr[k * 64];
        Pi[k] = pi[k * 64];
    }
    __syncthreads();
    for (int hh = 0; hh < 8; ++hh) {
        const int hl = hg * 8 + hh;
        float ar = 0.f, ai = 0.f;
#pragma unroll
        for (int k4 = 0; k4 < 8; ++k4) {
            const float4 hr4 = *(const float4*)&lhr[hl * 32 + k4 * 4];
            const float4 hi4 = *(const float4*)&lhi[hl * 32 + k4 * 4];
            ar = fmaf(Pr[k4*4+0], hr4.x, fmaf(Pi[k4*4+0], hi4.x, ar));
            ai = fmaf(Pi[k4*4+0], hr4.x, fmaf(-Pr[k4*4+0], hi4.x, ai));
            ar = fmaf(Pr[k4*4+1], hr4.y, fmaf(Pi[k4*4+1], hi4.y, ar));
            ai = fmaf(Pi[k4*4+1], hr4.y, fmaf(-Pr[k4*4+1], hi4.y, ai));
            ar = fmaf(Pr[k4*4+2], hr4.z, fmaf(Pi[k4*4+2], hi4.z, ar));
            ai = fmaf(Pi[k4*4+2], hr4.z, fmaf(-Pr[k4*4+2], hi4.z, ai));
            ar = fmaf(Pr[k4*4+3], hr4.w, fmaf(Pi[k4*4+3], hi4.w, ar));
            ai = fmaf(Pi[k4*4+3], hr4.w, fmaf(-Pr[k4*4+3], hi4.w, ai));
        }
        const int h = hq * 32 + hl;
        const size_t rb = ((size_t)(b * 256 + h) * 64 + o) * 64;
        recO[rb + m]      = f2b(ar);
        recO[rb + 32 + m] = f2b(ai);
    }
}

// K7: MFMA fused final. grid = B*H*4. T14 prefetch of mw/scw.
__global__ __launch_bounds__(256) void k_final4(
    const float* __restrict__ x,
    const unsigned short* __restrict__ wb_bf,
    const unsigned short* __restrict__ recO,
    const float* __restrict__ mw, const float* __restrict__ mb,
    const float* __restrict__ scw, const float* __restrict__ scb,
    float* __restrict__ out)
{
    constexpr int LD = 72;
    __shared__ __align__(16) unsigned short sWb[64 * LD];
    __shared__ __align__(16) unsigned short sR [64 * LD];
    __shared__ __align__(16) unsigned short sX [64 * LD];
    __shared__ __align__(16) unsigned short sS [64 * LD];
    const int blk = blockIdx.x;
    const int b = blk >> 10, h = (blk >> 2) & 255, wq = blk & 3;
    const int w0 = wq * 64;
    const int t = threadIdx.x;
    const int lane = t & 63, wv = t >> 6;
    const size_t pixbase = (size_t)(b * 256 + h) * 256 + w0;

    // T14: issue mw/scw loads now; consumed after phase A
    float4 mwv[4], scv[4];
#pragma unroll
    for (int r = 0; r < 4; ++r) {
        const int idx = r * 256 + t;
        const int o = idx >> 4, cq2 = idx & 15;
        mwv[r] = *(const float4*)&mw[o * 64 + cq2 * 4];
        scv[r] = *(const float4*)&scw[o * 64 + cq2 * 4];
    }

#pragma unroll
    for (int r = 0; r < 2; ++r) {
        const int idx = r * 256 + t;
        const int px = idx >> 3, f = idx & 7;
        *(uint4*)&sWb[px * LD + f * 8] = *(const uint4*)&wb_bf[(pixbase + px) * 64 + f * 8];
    }
    const size_t recbase = (size_t)(b * 256 + h) * 4096;
#pragma unroll
    for (int r = 0; r < 2; ++r) {
        const int idx = r * 256 + t;
        const int o = idx >> 3, f = idx & 7;
        *(uint4*)&sR[o * LD + f * 8] = *(const uint4*)&recO[recbase + (size_t)o * 64 + f * 8];
    }
    stage_xT(x, sX, b, h, w0, t, LD);
    __syncthreads();

    const int arow = lane & 15;
    const int koff = (lane >> 4) * 8;
    const f32x4 zero = {0.f, 0.f, 0.f, 0.f};

    f32x4 accA[4] = {zero, zero, zero, zero};
#pragma unroll
    for (int kc = 0; kc < 2; ++kc) {
        const bf16x8 a = *(const bf16x8*)&sR[(16 * wv + arow) * LD + kc * 32 + koff];
#pragma unroll
        for (int nt = 0; nt < 4; ++nt) {
            const bf16x8 bb = *(const bf16x8*)&sWb[(nt * 16 + arow) * LD + kc * 32 + koff];
            accA[nt] = __builtin_amdgcn_mfma_f32_16x16x32_bf16(a, bb, accA[nt], 0, 0, 0);
        }
    }
    __syncthreads();

    const int crow = 16 * wv + (lane >> 4) * 4;
#pragma unroll
    for (int nt = 0; nt < 4; ++nt) {
        const int px = nt * 16 + arow;
#pragma unroll
        for (int j = 0; j < 4; ++j)
            sS[px * LD + crow + j] = f2b(accA[nt][j] * (1.0f / 65536.0f));
    }
#pragma unroll
    for (int r = 0; r < 4; ++r) {
        const int idx = r * 256 + t;
        const int o = idx >> 4, cq2 = idx & 15;
        ushort4 u1;
        u1.x = f2b(mwv[r].x); u1.y = f2b(mwv[r].y); u1.z = f2b(mwv[r].z); u1.w = f2b(mwv[r].w);
        *(ushort4*)&sWb[o * LD + cq2 * 4] = u1;
        ushort4 u2;
        u2.x = f2b(scv[r].x); u2.y = f2b(scv[r].y); u2.z = f2b(scv[r].z); u2.w = f2b(scv[r].w);
        *(ushort4*)&sR[o * LD + cq2 * 4] = u2;
    }
    __syncthreads();

    f32x4 accB[4] = {zero, zero, zero, zero};
    f32x4 accC[4] = {zero, zero, zero, zero};
#pragma unroll
    for (int kc = 0; kc < 2; ++kc) {
        const bf16x8 am = *(const bf16x8*)&sWb[(16 * wv + arow) * LD + kc * 32 + koff];
        const bf16x8 as = *(const bf16x8*)&sR [(16 * wv + arow) * LD + kc * 32 + koff];
#pragma unroll
        for (int nt = 0; nt < 4; ++nt) {
            const bf16x8 bs = *(const bf16x8*)&sS[(nt * 16 + arow) * LD + kc * 32 + koff];
            const bf16x8 bx = *(const bf16x8*)&sX[(nt * 16 + arow) * LD + kc * 32 + koff];
            accB[nt] = __builtin_amdgcn_mfma_f32_16x16x32_bf16(am, bs, accB[nt], 0, 0, 0);
            accC[nt] = __builtin_amdgcn_mfma_f32_16x16x32_bf16(as, bx, accC[nt], 0, 0, 0);
        }
    }

#pragma unroll
    for (int nt = 0; nt < 4; ++nt) {
        const int px = nt * 16 + arow;
#pragma unroll
        for (int j = 0; j < 4; ++j) {
            const int o = crow + j;
            const float y = gelu_f(accB[nt][j] + mb[o]);
            const float z = y + accC[nt][j] + scb[o];
            out[((size_t)(b * 64 + o) * 256 + h) * 256 + w0 + px] = gelu_f(z);
        }
    }
}

extern "C" void kernel_launch(void* const* d_in, const int* in_sizes, int n_in,
                              void* d_out, int out_size, void* d_ws, size_t ws_size,
                              hipStream_t stream) {
    const float* x    = (const float*)d_in[0];
    const float* wW0  = (const float*)d_in[1];
    const float* wb0  = (const float*)d_in[2];
    const float* wW1  = (const float*)d_in[3];
    const float* wb1  = (const float*)d_in[4];
    const float* wW2  = (const float*)d_in[5];
    const float* wb2  = (const float*)d_in[6];
    const float* hW0  = (const float*)d_in[7];
    const float* hb0  = (const float*)d_in[8];
    const float* hW1  = (const float*)d_in[9];
    const float* hb1  = (const float*)d_in[10];
    const float* hW2  = (const float*)d_in[11];
    const float* hb2  = (const float*)d_in[12];
    const float* Wf_re = (const float*)d_in[13];
    const float* Wf_im = (const float*)d_in[14];
    const float* mw   = (const float*)d_in[15];
    const float* mbv  = (const float*)d_in[16];
    const float* scw  = (const float*)d_in[17];
    const float* scb  = (const float*)d_in[18];

    char* base = (char*)d_ws;
    unsigned short* wb_bf = (unsigned short*)(base + 0);            // 33,554,432
    unsigned short* tfwM  = (unsigned short*)(base + 33554432);     //  8,388,608 (bf16)
    unsigned short* hb_bf = (unsigned short*)(base + 41943040);     //  4,194,304
    float* tfhw_p = (float*)(base + 46137344);                      //  8,388,608 (4 parts)
    float* tfhw   = (float*)(base + 54525952);                      //  2,097,152 (re||im)
    float* proc_p = (float*)(base + 56623104);                      //  4,194,304 (2 parts)
    float* procT  = (float*)(base + 60817408);                      //  2,097,152 (re||im)
    unsigned short* recO = (unsigned short*)(base + 62914560);      //  8,388,608
    unsigned short* wT0 = (unsigned short*)(base + 71303168);       //     12,288
    unsigned short* wT1 = (unsigned short*)(base + 71315456);       //      8,192
    unsigned short* wT2 = (unsigned short*)(base + 71323648);
    unsigned short* hT0 = (unsigned short*)(base + 71331840);
    unsigned short* hT1 = (unsigned short*)(base + 71344128);
    unsigned short* hT2 = (unsigned short*)(base + 71352320);
    // total ~71.4 MB

    k_prep<<<1, 256, 0, stream>>>(wW0, wW1, wW2, hW0, hW1, hW2,
                                  wT0, wT1, wT2, hT0, hT1, hT2);
    k_wbtfw<<<1024, 256, 0, stream>>>(x, wT0, wb0, wT1, wb1, wT2, wb2,
                                      wb_bf, tfwM);
    k_hbtfhw<<<512, 256, 0, stream>>>(tfwM, hT0, hb0, hT1, hb1, hT2, hb2,
                                      hb_bf, tfhw_p);
    k_psum<<<1024, 256, 0, stream>>>(tfhw_p, tfhw, 4, 524288);
    k_proc2<<<512, 256, 0, stream>>>(tfhw, Wf_re, Wf_im, proc_p);
    k_psum_procT<<<1024, 256, 0, stream>>>(proc_p, procT);
    k_rec4<<<1024, 256, 0, stream>>>(procT, hb_bf, recO);
    k_final4<<<4096, 256, 0, stream>>>(x, wb_bf, recO, mw, mbv, scw, scb,
                                       (float*)d_out);
}